// Round 14
// baseline (1192.629 us; speedup 1.0000x reference)
//
#include <hip/hip_runtime.h>
#include <hip/hip_bf16.h>

// ---------------- constants ----------------
static constexpr int kL = 12;
static constexpr int kD = 384;
static constexpr int kH = 6;
static constexpr int kB = 64;
static constexpr int kNP = 196;      // patches
static constexpr int kBAND = 197;    // tokens incl cls (max)
static constexpr int kNCLS = 1000;
static constexpr float kSCALE = 0.125f;   // 64^-0.5
static constexpr float kEPS = 1e-6f;
static constexpr size_t kWQ = (size_t)kB * kH * kBAND * 64;   // per-tensor elems in split qkv
static constexpr int kBH = kB * kH;                            // 384

typedef __attribute__((ext_vector_type(8))) short short8;
typedef __attribute__((ext_vector_type(4))) float f32x4;

__device__ __forceinline__ float gelu_f(float x) {
    return 0.5f * x * (1.0f + erff(x * 0.70710678118654752440f));
}
__device__ __forceinline__ unsigned short f2bf(float x) {
    __hip_bfloat16 h = __float2bfloat16(x);
    return *(unsigned short*)&h;
}
__device__ __forceinline__ float bf2f(unsigned short u) {
    unsigned int x = ((unsigned int)u) << 16;
    return __uint_as_float(x);
}

// ---------------- init: state + cls rows of xtA (bf16) + cls-row LN partials ----------------
__global__ __launch_bounds__(384) void k_init(int* si, float* sf,
                                              const float* __restrict__ cls,
                                              const float* __restrict__ pos,
                                              unsigned short* __restrict__ xtA,
                                              float2* __restrict__ pstats) {
    int b = blockIdx.x, c = threadIdx.x;
    unsigned short hv = f2bf(cls[c] + pos[c]);
    xtA[(size_t)b * kBAND * kD + c] = hv;
    float v = bf2f(hv);                      // stats of the ROUNDED value
    __shared__ float r1[384], r2[384];
    r1[c] = v; r2[c] = v * v;
    __syncthreads();
    if (c < 128) { r1[c] += r1[c + 128] + r1[c + 256]; r2[c] += r2[c + 128] + r2[c + 256]; }
    __syncthreads();
    for (int st = 64; st; st >>= 1) {
        if (c < st) { r1[c] += r1[c + st]; r2[c] += r2[c + st]; }
        __syncthreads();
    }
    if (c == 0) {
        pstats[(size_t)(b * kBAND) * 8 + 0] = make_float2(r1[0], r2[0]);
#pragma unroll
        for (int nn = 1; nn < 6; ++nn) pstats[(size_t)(b * kBAND) * 8 + nn] = make_float2(0.f, 0.f);
        if (b == 0) { si[0] = kBAND; sf[0] = 1.0f; }
    }
}

// ---------------- fp32 -> bf16 weight conversion (all 5 tensors, one launch) ----------------
__global__ __launch_bounds__(256) void k_cvtall(
    const float* __restrict__ s0, const float* __restrict__ s1, const float* __restrict__ s2,
    const float* __restrict__ s3, const float* __restrict__ s4,
    __hip_bfloat16* __restrict__ d0, __hip_bfloat16* __restrict__ d1, __hip_bfloat16* __restrict__ d2,
    __hip_bfloat16* __restrict__ d3, __hip_bfloat16* __restrict__ d4) {
    const int c0 = 73728, c1 = 1400832, c2 = 1843200, c3 = 3612672, c4 = 5382144;
    int stride = gridDim.x * 256;
    for (int i = blockIdx.x * 256 + threadIdx.x; i < c4; i += stride) {
        const float* src; __hip_bfloat16* dst; int off;
        if (i < c0)      { src = s0; dst = d0; off = i; }
        else if (i < c1) { src = s1; dst = d1; off = i - c0; }
        else if (i < c2) { src = s2; dst = d2; off = i - c1; }
        else if (i < c3) { src = s3; dst = d3; off = i - c2; }
        else             { src = s4; dst = d4; off = i - c3; }
        float4 v = ((const float4*)src)[off];
        dst[4 * off + 0] = __float2bfloat16(v.x);
        dst[4 * off + 1] = __float2bfloat16(v.y);
        dst[4 * off + 2] = __float2bfloat16(v.z);
        dst[4 * off + 3] = __float2bfloat16(v.w);
    }
}

// ---------------- bf16 MFMA GEMM: 64x64 block tile (proven geometry) ----------------
// XCD-pinned 1-D grid: L -> (xcd=L&7, n=(L>>3)%nT, r=((L>>3)/nT)*8+xcd).
// Virtual row compaction: rv in [0,64*Nt) -> (b=rv/Nt, t=rv%Nt), phys row b*band+t.
// Residual stream is BF16 everywhere.
// LNA==1: A is bf16 residual; per-row LN stats from pstatsIn, normalize-on-stage.
// STATS==1 (bf16 out): store pass emits per-(row, 64-col-slice) (sum,sumsq) of the
//                      ROUNDED stored values into pstatsOut (8-lane shfl per row).
// MODE: 0 normal (R bf16 residual, keepR gather), 1 qkv head-split store,
//       2 patch: A loaded on-the-fly from fp32 image (im2col fused), +patch_b, +pos(fp32),
//                store to xtA row t+1.
template<int ACT_GELU, int MODE, int LNA, int STATS>
__global__ __launch_bounds__(256) void k_mgemm(
    const void* __restrict__ Av, int lda,
    const unsigned short* __restrict__ W, int K,
    const float* __restrict__ bias,
    unsigned short* __restrict__ Cv, int ldc,
    const void* __restrict__ Rv,
    const int* __restrict__ keepR,
    const float* __restrict__ lnw, const float* __restrict__ lnb,
    int rT, int nT, int band,
    const int* __restrict__ NtPtr, int ntConst,
    const float2* __restrict__ pstatsIn, float2* __restrict__ pstatsOut)
{
    __shared__ __align__(16) unsigned char pool[18432];
    unsigned short (*As)[72] = (unsigned short (*)[72])pool;
    unsigned short (*Ws)[72] = (unsigned short (*)[72])(pool + 9216);
    unsigned short (*Cu)[76] = (unsigned short (*)[76])pool;   // 64x76 u16 overlay
    __shared__ float mus[64], rss[64];

    int Nt = NtPtr ? NtPtr[0] : ntConst;
    unsigned int rowsTotal = (unsigned int)kB * (unsigned int)Nt;

    int L = blockIdx.x;
    int xcd = L & 7;
    int m = L >> 3;
    int n = m % nT;
    int r = (m / nT) * 8 + xcd;
    if (r >= rT) return;
    unsigned int r0 = (unsigned int)r * 64;
    int n0 = n * 64;
    if (r0 >= rowsTotal) return;

    const float* Rf = (const float*)Rv;                 // MODE 2: pos (fp32)
    const unsigned short* Rb = (const unsigned short*)Rv;  // MODE 0: residual (bf16)

    int tid = threadIdx.x;
    int srow = tid >> 3;            // 0..31
    int scol = (tid & 7) << 3;      // 0..56 step 8

    unsigned int rv0 = r0 + srow, rv1 = r0 + srow + 32;
    bool v0 = rv0 < rowsTotal, v1 = rv1 < rowsTotal;
    const unsigned short* ah0 = nullptr; const unsigned short* ah1 = nullptr;
    const float* xb0 = nullptr; const float* xb1 = nullptr;   // MODE 2 image bases
    if (MODE == 2) {
        if (v0) {
            unsigned int bb = rv0 / (unsigned int)Nt, tt = rv0 - bb * Nt;
            int py = tt / 14, px = tt - py * 14;
            xb0 = (const float*)Av + (size_t)bb * 3 * 224 * 224 + (py * 16) * 224 + px * 16;
        }
        if (v1) {
            unsigned int bb = rv1 / (unsigned int)Nt, tt = rv1 - bb * Nt;
            int py = tt / 14, px = tt - py * 14;
            xb1 = (const float*)Av + (size_t)bb * 3 * 224 * 224 + (py * 16) * 224 + px * 16;
        }
    } else {
        if (v0) {
            unsigned int bb = rv0 / (unsigned int)Nt, tt = rv0 - bb * Nt;
            ah0 = (const unsigned short*)Av + ((size_t)bb * band + tt) * lda;
        }
        if (v1) {
            unsigned int bb = rv1 / (unsigned int)Nt, tt = rv1 - bb * Nt;
            ah1 = (const unsigned short*)Av + ((size_t)bb * band + tt) * lda;
        }
    }
    const unsigned short* wp0 = W + (size_t)(n0 + srow) * K;
    const unsigned short* wp1 = W + (size_t)(n0 + srow + 32) * K;

    float mu0 = 0.f, rs0 = 0.f, mu1 = 0.f, rs1 = 0.f;
    if (LNA) {
        if (tid < 64) {
            unsigned int rv = r0 + tid;
            float mu = 0.f, rsd = 0.f;
            if (rv < rowsTotal) {
                unsigned int bb = rv / (unsigned int)Nt, tt = rv - bb * Nt;
                const float2* ps = pstatsIn + ((size_t)bb * band + tt) * 8;
                float s1 = 0.f, s2 = 0.f;
#pragma unroll
                for (int nn = 0; nn < 6; ++nn) { float2 p = ps[nn]; s1 += p.x; s2 += p.y; }
                mu = s1 * (1.f / 384.f);
                float var = fmaxf(s2 * (1.f / 384.f) - mu * mu, 0.f);
                rsd = rsqrtf(var + kEPS);
            }
            mus[tid] = mu; rss[tid] = rsd;
        }
        __syncthreads();
        mu0 = mus[srow]; rs0 = rss[srow];
        mu1 = mus[srow + 32]; rs1 = rss[srow + 32];
    }

    int wave = tid >> 6, lane = tid & 63;
    int wr32 = ((wave >> 1) & 1) * 32, wc32 = (wave & 1) * 32;
    int l15 = lane & 15, l4 = lane >> 4;

    f32x4 acc00 = {}, acc01 = {}, acc10 = {}, acc11 = {};

    for (int k0 = 0; k0 < K; k0 += 64) {
        uint4 zero = make_uint4(0, 0, 0, 0);
        uint4 a0 = zero, a1 = zero;
        uint4 w0 = *(const uint4*)(wp0 + k0 + scol);
        uint4 w1 = *(const uint4*)(wp1 + k0 + scol);
        if (MODE == 2) {
            int k = k0 + scol;
            int c = k >> 8;
            int rr_ = k & 255;
            int ky = rr_ >> 4, kx = rr_ & 15;
            size_t off = (size_t)c * 50176 + (size_t)ky * 224 + kx;
            if (v0) {
                float4 x0 = *(const float4*)(xb0 + off);
                float4 x1 = *(const float4*)(xb0 + off + 4);
                unsigned short p[8];
                p[0] = f2bf(x0.x); p[1] = f2bf(x0.y); p[2] = f2bf(x0.z); p[3] = f2bf(x0.w);
                p[4] = f2bf(x1.x); p[5] = f2bf(x1.y); p[6] = f2bf(x1.z); p[7] = f2bf(x1.w);
                a0 = *(uint4*)p;
            }
            if (v1) {
                float4 x0 = *(const float4*)(xb1 + off);
                float4 x1 = *(const float4*)(xb1 + off + 4);
                unsigned short p[8];
                p[0] = f2bf(x0.x); p[1] = f2bf(x0.y); p[2] = f2bf(x0.z); p[3] = f2bf(x0.w);
                p[4] = f2bf(x1.x); p[5] = f2bf(x1.y); p[6] = f2bf(x1.z); p[7] = f2bf(x1.w);
                a1 = *(uint4*)p;
            }
        } else if (LNA) {
            float4 lw0 = *(const float4*)(lnw + k0 + scol);
            float4 lw1 = *(const float4*)(lnw + k0 + scol + 4);
            float4 lb0 = *(const float4*)(lnb + k0 + scol);
            float4 lb1 = *(const float4*)(lnb + k0 + scol + 4);
            if (v0) {
                uint4 raw = *(const uint4*)(ah0 + k0 + scol);
                const unsigned short* u = (const unsigned short*)&raw;
                unsigned short p[8];
                p[0] = f2bf((bf2f(u[0]) - mu0) * rs0 * lw0.x + lb0.x);
                p[1] = f2bf((bf2f(u[1]) - mu0) * rs0 * lw0.y + lb0.y);
                p[2] = f2bf((bf2f(u[2]) - mu0) * rs0 * lw0.z + lb0.z);
                p[3] = f2bf((bf2f(u[3]) - mu0) * rs0 * lw0.w + lb0.w);
                p[4] = f2bf((bf2f(u[4]) - mu0) * rs0 * lw1.x + lb1.x);
                p[5] = f2bf((bf2f(u[5]) - mu0) * rs0 * lw1.y + lb1.y);
                p[6] = f2bf((bf2f(u[6]) - mu0) * rs0 * lw1.z + lb1.z);
                p[7] = f2bf((bf2f(u[7]) - mu0) * rs0 * lw1.w + lb1.w);
                a0 = *(uint4*)p;
            }
            if (v1) {
                uint4 raw = *(const uint4*)(ah1 + k0 + scol);
                const unsigned short* u = (const unsigned short*)&raw;
                unsigned short p[8];
                p[0] = f2bf((bf2f(u[0]) - mu1) * rs1 * lw0.x + lb0.x);
                p[1] = f2bf((bf2f(u[1]) - mu1) * rs1 * lw0.y + lb0.y);
                p[2] = f2bf((bf2f(u[2]) - mu1) * rs1 * lw0.z + lb0.z);
                p[3] = f2bf((bf2f(u[3]) - mu1) * rs1 * lw0.w + lb0.w);
                p[4] = f2bf((bf2f(u[4]) - mu1) * rs1 * lw1.x + lb1.x);
                p[5] = f2bf((bf2f(u[5]) - mu1) * rs1 * lw1.y + lb1.y);
                p[6] = f2bf((bf2f(u[6]) - mu1) * rs1 * lw1.z + lb1.z);
                p[7] = f2bf((bf2f(u[7]) - mu1) * rs1 * lw1.w + lb1.w);
                a1 = *(uint4*)p;
            }
        } else {
            a0 = v0 ? *(const uint4*)(ah0 + k0 + scol) : zero;
            a1 = v1 ? *(const uint4*)(ah1 + k0 + scol) : zero;
        }
        __syncthreads();
        *(uint4*)&As[srow][scol] = a0;
        *(uint4*)&As[srow + 32][scol] = a1;
        *(uint4*)&Ws[srow][scol] = w0;
        *(uint4*)&Ws[srow + 32][scol] = w1;
        __syncthreads();
#pragma unroll
        for (int ks = 0; ks < 2; ++ks) {
            short8 af_0 = *(const short8*)&As[wr32 + l15][ks * 32 + l4 * 8];
            short8 af_1 = *(const short8*)&As[wr32 + 16 + l15][ks * 32 + l4 * 8];
            short8 bf_0 = *(const short8*)&Ws[wc32 + l15][ks * 32 + l4 * 8];
            short8 bf_1 = *(const short8*)&Ws[wc32 + 16 + l15][ks * 32 + l4 * 8];
            acc00 = __builtin_amdgcn_mfma_f32_16x16x32_bf16(af_0, bf_0, acc00, 0, 0, 0);
            acc01 = __builtin_amdgcn_mfma_f32_16x16x32_bf16(af_0, bf_1, acc01, 0, 0, 0);
            acc10 = __builtin_amdgcn_mfma_f32_16x16x32_bf16(af_1, bf_0, acc10, 0, 0, 0);
            acc11 = __builtin_amdgcn_mfma_f32_16x16x32_bf16(af_1, bf_1, acc11, 0, 0, 0);
        }
    }

    // -------- epilogue: bias/act/residual, stage tile (bf16) in LDS --------
    __syncthreads();
    f32x4 accs[2][2] = { { acc00, acc01 }, { acc10, acc11 } };
#pragma unroll
    for (int fi = 0; fi < 2; ++fi) {
        int lrow = wr32 + fi * 16 + l4 * 4;
        unsigned int rvb = r0 + lrow;
#pragma unroll
        for (int fj = 0; fj < 2; ++fj) {
            int lcol = wc32 + fj * 16 + l15;
            float bv = bias ? bias[n0 + lcol] : 0.f;
#pragma unroll
            for (int rr = 0; rr < 4; ++rr) {
                unsigned int rv = rvb + rr;
                float v = accs[fi][fj][rr] + bv;
                if (ACT_GELU) v = gelu_f(v);
                if (MODE == 2) {
                    if (rv < rowsTotal) {
                        unsigned int bb = rv / (unsigned int)Nt;
                        unsigned int tt = rv - bb * (unsigned int)Nt;
                        v += Rf[(size_t)(tt + 1) * kD + n0 + lcol];
                    }
                } else if (Rv && rv < rowsTotal) {
                    unsigned int bb = rv / (unsigned int)Nt;
                    unsigned int tt = rv - bb * (unsigned int)Nt;
                    size_t rrow = keepR ? ((size_t)bb * band + keepR[tt]) : ((size_t)bb * band + tt);
                    v += bf2f(Rb[rrow * ldc + n0 + lcol]);
                }
                Cu[lrow + rr][lcol] = f2bf(v);
            }
        }
    }
    __syncthreads();

    // -------- coalesced stores (+ optional LN partial-stats emit) --------
#pragma unroll
    for (int i = 0; i < 2; ++i) {
        int id = tid + (i << 8);
        int row = id >> 3, c2 = id & 7;
        unsigned int rv = r0 + row;
        if (rv < rowsTotal) {
            unsigned int bb = rv / (unsigned int)Nt;
            unsigned int tt = rv - bb * (unsigned int)Nt;
            uint4 val = *(const uint4*)&Cu[row][c2 << 3];
            if (MODE == 1) {
                int which = n0 >= 768 ? 2 : (n0 >= 384 ? 1 : 0);
                int hh = (n0 - which * 384) >> 6;
                *(uint4*)(Cv + (size_t)which * kWQ +
                          (((size_t)bb * kH + hh) * kBAND + tt) * 64 + ((n0 & 63) + (c2 << 3))) = val;
            } else if (MODE == 2) {
                *(uint4*)(Cv + ((size_t)bb * kBAND + tt + 1) * ldc + n0 + (c2 << 3)) = val;
            } else {
                *(uint4*)(Cv + ((size_t)bb * band + tt) * ldc + n0 + (c2 << 3)) = val;
            }
            if (STATS) {
                const unsigned short* u = (const unsigned short*)&val;
                float s1 = 0.f, s2 = 0.f;
#pragma unroll
                for (int e = 0; e < 8; ++e) { float f = bf2f(u[e]); s1 += f; s2 += f * f; }
#pragma unroll
                for (int off = 1; off < 8; off <<= 1) {
                    s1 += __shfl_xor(s1, off, 64);
                    s2 += __shfl_xor(s2, off, 64);
                }
                if (c2 == 0) {
                    size_t sridx = (MODE == 2) ? ((size_t)bb * kBAND + tt + 1)
                                               : ((size_t)bb * band + tt);
                    pstatsOut[sridx * 8 + n] = make_float2(s1, s2);
                }
            }
        }
    }
}

// ---------------- decision A: per-(b,h) importance; imph stored TRANSPOSED [token][bh] ------
__global__ __launch_bounds__(256) void k_decA(const __hip_bfloat16* __restrict__ qsplit,
                                              float* __restrict__ imph, float* __restrict__ sabh,
                                              const int* __restrict__ si) {
    int Nt = si[0];
    if (Nt - 1 <= 16) return;
    int tid = threadIdx.x, w = tid >> 6, lane = tid & 63;
    int bh = blockIdx.x;
    __shared__ float qs[64];
    __shared__ float sdot[224], svn[224];
    __shared__ float red[256];
    const __hip_bfloat16* qp = qsplit + (size_t)bh * kBAND * 64;
    const __hip_bfloat16* kp = qsplit + kWQ + (size_t)bh * kBAND * 64;
    const __hip_bfloat16* vp = qsplit + 2 * kWQ + (size_t)bh * kBAND * 64;
    if (tid < 64) qs[tid] = __bfloat162float(qp[tid]);   // cls q
    __syncthreads();
    float qv = qs[lane];
    for (int j = w; j < Nt; j += 8) {
        int j2 = j + 4;
        bool has2 = j2 < Nt;
        float k1 = __bfloat162float(kp[(size_t)j * 64 + lane]);
        float v1 = __bfloat162float(vp[(size_t)j * 64 + lane]);
        float k2 = has2 ? __bfloat162float(kp[(size_t)j2 * 64 + lane]) : 0.f;
        float v2 = has2 ? __bfloat162float(vp[(size_t)j2 * 64 + lane]) : 0.f;
        float p1 = qv * k1, n1 = v1 * v1;
        float p2 = qv * k2, n2 = v2 * v2;
#pragma unroll
        for (int off = 1; off < 64; off <<= 1) {
            p1 += __shfl_xor(p1, off, 64); n1 += __shfl_xor(n1, off, 64);
            p2 += __shfl_xor(p2, off, 64); n2 += __shfl_xor(n2, off, 64);
        }
        if (lane == 0) {
            sdot[j] = p1 * kSCALE; svn[j] = sqrtf(n1);
            if (has2) { sdot[j2] = p2 * kSCALE; svn[j2] = sqrtf(n2); }
        }
    }
    __syncthreads();
    float s = (tid < Nt) ? sdot[tid] : -INFINITY;
    red[tid] = s; __syncthreads();
    for (int st = 128; st; st >>= 1) { if (tid < st) red[tid] = fmaxf(red[tid], red[tid + st]); __syncthreads(); }
    float mmax = red[0]; __syncthreads();
    float e = (tid < Nt) ? expf(s - mmax) : 0.f;
    red[tid] = e; __syncthreads();
    for (int st = 128; st; st >>= 1) { if (tid < st) red[tid] += red[tid + st]; __syncthreads(); }
    float inv = 1.f / red[0];
    float val = (tid < Nt) ? e * inv * svn[tid] : 0.f;
    if (tid < Nt) imph[(size_t)tid * kBH + bh] = val;    // transposed
    __syncthreads();
    red[tid] = val; __syncthreads();
    for (int st = 128; st; st >>= 1) { if (tid < st) red[tid] += red[tid + st]; __syncthreads(); }
    if (tid == 0) { sabh[2 * bh] = red[0]; sabh[2 * bh + 1] = val; }   // tid0 val = token 0
}

// ---------------- decision B: finalize (1 block): mass/ratio, top-k, keep, commit Nt --------
__global__ __launch_bounds__(256) void k_decB(int* __restrict__ si, float* __restrict__ sf,
                                              const float* __restrict__ imph,
                                              const float* __restrict__ sabh,
                                              int* __restrict__ keep) {
    int Nt = si[0];
    int tid = threadIdx.x;
    if (Nt - 1 <= 16) {
        for (int j = tid; j < Nt; j += 256) keep[j] = j;
        return;
    }
    int N = Nt - 1;
    __shared__ float red[256];
    float v = 0.f;
    if (tid < kB) {
        float sa = 0.f, i0 = 0.f;
#pragma unroll
        for (int hh = 0; hh < kH; ++hh) {
            sa += sabh[2 * (tid * kH + hh)];
            i0 += sabh[2 * (tid * kH + hh) + 1];
        }
        sa *= (1.f / 6.f); i0 *= (1.f / 6.f);
        v = (sa - i0) / (sa + kEPS);
    }
    red[tid] = v; __syncthreads();
    for (int st = 128; st; st >>= 1) { if (tid < st) red[tid] += red[tid + st]; __syncthreads(); }
    float mass = red[0] * (1.f / 64.f);
    float prev = sf[0];
    float ratio = 0.5f * mass / (prev + kEPS);
    ratio = fminf(fmaxf(ratio, 0.f), 1.f);
    int N_next = (int)((double)N * (double)ratio);
    if (N_next < 16) N_next = 16;
    if (tid == 0) sf[0] = mass;
    __syncthreads();
    if (N_next >= N) {
        for (int j = tid; j < Nt; j += 256) keep[j] = j;
        return;
    }
    __shared__ float scq[200][4];
    __shared__ float sc[200];
    __shared__ int flag[200];
    for (int task = tid; task < N * 4; task += 256) {
        int row = task >> 2, seg = task & 3;
        const float4* p = (const float4*)(imph + (size_t)(row + 1) * kBH) + seg * 24;
        float a0 = 0.f, a1 = 0.f, a2 = 0.f, a3 = 0.f;
#pragma unroll
        for (int q = 0; q < 24; q += 4) {
            float4 x0 = p[q + 0], x1 = p[q + 1], x2 = p[q + 2], x3 = p[q + 3];
            a0 += (x0.x + x0.y) + (x0.z + x0.w);
            a1 += (x1.x + x1.y) + (x1.z + x1.w);
            a2 += (x2.x + x2.y) + (x2.z + x2.w);
            a3 += (x3.x + x3.y) + (x3.z + x3.w);
        }
        scq[row][seg] = (a0 + a1) + (a2 + a3);
    }
    __syncthreads();
    if (tid < N) sc[tid] = (scq[tid][0] + scq[tid][1]) + (scq[tid][2] + scq[tid][3]);
    __syncthreads();
    if (tid < N) {
        float s2 = sc[tid];
        int rank = 0;
        for (int i = 0; i < N; ++i) {
            float o2 = sc[i];
            rank += (o2 > s2) || (o2 == s2 && i < tid);
        }
        flag[tid] = (rank < N_next) ? 1 : 0;
    }
    __syncthreads();
    if (tid == 0) {
        keep[0] = 0;
        int pos = 1;
        for (int j = 0; j < N; ++j) if (flag[j]) keep[pos++] = j + 1;
        si[0] = N_next + 1;
    }
}

// ---------------- MFMA flash attention: one block per (b,h) (bf16 qsplit) ----------------
__global__ __launch_bounds__(256) void k_attn2(const __hip_bfloat16* __restrict__ qsplit,
                                               __hip_bfloat16* __restrict__ o,
                                               const int* __restrict__ si,
                                               const int* __restrict__ keep) {
    __shared__ __align__(16) unsigned short Kb[224][72];
    __shared__ __align__(16) unsigned short Vt[64][228];
    __shared__ __align__(16) unsigned short Pb[4][16][228];
    int Nt = si[0];
    int bh = blockIdx.x;
    int b = bh / kH, h = bh - b * kH;
    int tid = threadIdx.x, w = tid >> 6, lane = tid & 63;
    int l15 = lane & 15, l4 = lane >> 4;
    int nJT = (Nt + 15) >> 4;
    int nKT = (Nt + 31) >> 5;
    int NTP = nKT << 5;

    const unsigned short* qb = (const unsigned short*)qsplit + (size_t)bh * kBAND * 64;
    const unsigned short* kb = (const unsigned short*)qsplit + kWQ + (size_t)bh * kBAND * 64;
    const unsigned short* vb = (const unsigned short*)qsplit + 2 * kWQ + (size_t)bh * kBAND * 64;

    {
        int rr = tid >> 3;
        int c8 = (tid & 7) << 3;
        for (int r = rr; r < NTP; r += 32) {
            uint4 kv = make_uint4(0, 0, 0, 0), vv = make_uint4(0, 0, 0, 0);
            if (r < Nt) {
                int old = keep[r];
                kv = *(const uint4*)(kb + ((size_t)old << 6) + c8);
                vv = *(const uint4*)(vb + ((size_t)old << 6) + c8);
            }
            *(uint4*)&Kb[r][c8] = kv;
            const unsigned short* vs = (const unsigned short*)&vv;
#pragma unroll
            for (int e = 0; e < 8; ++e) Vt[c8 + e][r] = vs[e];
        }
    }
    __syncthreads();

    for (int strip = w; strip < nJT; strip += 4) {
        int tq = (strip << 4) + l15;
        int told = (tq < Nt) ? keep[tq] : 0;
        const unsigned short* qrow = qb + ((size_t)told << 6) + (l4 << 3);
        short8 qf0 = *(const short8*)(qrow);
        short8 qf1 = *(const short8*)(qrow + 32);

        f32x4 sv[13];
#pragma unroll
        for (int jt = 0; jt < 13; ++jt) {
            if (jt < nJT) {
                const unsigned short* kr = &Kb[(jt << 4) + l15][l4 << 3];
                short8 kf0 = *(const short8*)(kr);
                short8 kf1 = *(const short8*)(kr + 32);
                f32x4 a = {};
                a = __builtin_amdgcn_mfma_f32_16x16x32_bf16(qf0, kf0, a, 0, 0, 0);
                a = __builtin_amdgcn_mfma_f32_16x16x32_bf16(qf1, kf1, a, 0, 0, 0);
                sv[jt] = a;
            }
        }
        float mx[4] = { -INFINITY, -INFINITY, -INFINITY, -INFINITY };
#pragma unroll
        for (int jt = 0; jt < 13; ++jt) if (jt < nJT) {
            bool ok = ((jt << 4) + l15) < Nt;
#pragma unroll
            for (int r = 0; r < 4; ++r) {
                float s = ok ? sv[jt][r] * kSCALE : -INFINITY;
                sv[jt][r] = s;
                mx[r] = fmaxf(mx[r], s);
            }
        }
#pragma unroll
        for (int r = 0; r < 4; ++r) {
            mx[r] = fmaxf(mx[r], __shfl_xor(mx[r], 1, 64));
            mx[r] = fmaxf(mx[r], __shfl_xor(mx[r], 2, 64));
            mx[r] = fmaxf(mx[r], __shfl_xor(mx[r], 4, 64));
            mx[r] = fmaxf(mx[r], __shfl_xor(mx[r], 8, 64));
        }
        float sm[4] = { 0.f, 0.f, 0.f, 0.f };
#pragma unroll
        for (int jt = 0; jt < 13; ++jt) if (jt < nJT) {
#pragma unroll
            for (int r = 0; r < 4; ++r) {
                float p = expf(sv[jt][r] - mx[r]);
                sv[jt][r] = p;
                sm[r] += p;
            }
        }
#pragma unroll
        for (int r = 0; r < 4; ++r) {
            sm[r] += __shfl_xor(sm[r], 1, 64);
            sm[r] += __shfl_xor(sm[r], 2, 64);
            sm[r] += __shfl_xor(sm[r], 4, 64);
            sm[r] += __shfl_xor(sm[r], 8, 64);
            sm[r] = 1.f / sm[r];
        }
#pragma unroll
        for (int jt = 0; jt < 13; ++jt) if (jt < nJT) {
#pragma unroll
            for (int r = 0; r < 4; ++r)
                Pb[w][(l4 << 2) + r][(jt << 4) + l15] = f2bf(sv[jt][r] * sm[r]);
        }
        for (int c = (nJT << 4) + lane; c < NTP; c += 64) {
#pragma unroll
            for (int rr2 = 0; rr2 < 16; ++rr2) Pb[w][rr2][c] = 0;
        }
        asm volatile("s_waitcnt lgkmcnt(0)" ::: "memory");
        __builtin_amdgcn_sched_barrier(0);

        f32x4 oacc[4] = { {}, {}, {}, {} };
#pragma unroll
        for (int kt = 0; kt < 7; ++kt) if (kt < nKT) {
            short8 pf = *(const short8*)&Pb[w][l15][(kt << 5) + (l4 << 3)];
#pragma unroll
            for (int dt = 0; dt < 4; ++dt) {
                short8 vf = *(const short8*)&Vt[(dt << 4) + l15][(kt << 5) + (l4 << 3)];
                oacc[dt] = __builtin_amdgcn_mfma_f32_16x16x32_bf16(pf, vf, oacc[dt], 0, 0, 0);
            }
        }
#pragma unroll
        for (int dt = 0; dt < 4; ++dt) {
#pragma unroll
            for (int r = 0; r < 4; ++r) {
                int tqo = (strip << 4) + (l4 << 2) + r;
                if (tqo < Nt)
                    o[((size_t)b * kBAND + tqo) * kD + h * 64 + (dt << 4) + l15] =
                        __float2bfloat16(oacc[dt][r]);
            }
        }
    }
}

// ---------------- head with fused final LayerNorm (bf16 residual in) ----------------
__global__ __launch_bounds__(256) void k_head(const unsigned short* __restrict__ X,
                                              const float* __restrict__ nw, const float* __restrict__ nb,
                                              const float* __restrict__ hw, const float* __restrict__ hb,
                                              float* __restrict__ out) {
    int b = blockIdx.x >> 2;
    int tid = threadIdx.x;
    __shared__ float xs[384];
    __shared__ float red[256];
    const unsigned short* row = X + (size_t)b * kBAND * kD;
    float s1 = 0.f, s2 = 0.f;
    for (int c = tid; c < 384; c += 256) { float v = bf2f(row[c]); xs[c] = v; s1 += v; s2 += v * v; }
    red[tid] = s1; __syncthreads();
    for (int st = 128; st; st >>= 1) { if (tid < st) red[tid] += red[tid + st]; __syncthreads(); }
    float sum = red[0]; __syncthreads();
    red[tid] = s2; __syncthreads();
    for (int st = 128; st; st >>= 1) { if (tid < st) red[tid] += red[tid + st]; __syncthreads(); }
    float sq = red[0];
    float mu = sum * (1.f / 384.f);
    float var = fmaxf(sq * (1.f / 384.f) - mu * mu, 0.f);
    float rs = rsqrtf(var + kEPS);
    __syncthreads();
    for (int c = tid; c < 384; c += 256) xs[c] = (xs[c] - mu) * rs * nw[c] + nb[c];
    __syncthreads();
    int n = ((blockIdx.x & 3) << 8) + tid;
    if (n >= kNCLS) return;
    const float* wrow = hw + (size_t)n * kD;
    float acc = 0.f;
#pragma unroll 8
    for (int d = 0; d < kD; d += 4) {
        float4 w4 = *(const float4*)(wrow + d);
        acc += xs[d] * w4.x + xs[d + 1] * w4.y + xs[d + 2] * w4.z + xs[d + 3] * w4.w;
    }
    out[(size_t)b * kNCLS + n] = acc + hb[n];
}

// ---------------- host launch ----------------
extern "C" void kernel_launch(void* const* d_in, const int* in_sizes, int n_in,
                              void* d_out, int out_size, void* d_ws, size_t ws_size,
                              hipStream_t stream) {
    const float* x       = (const float*)d_in[0];
    const float* patch_w = (const float*)d_in[1];
    const float* patch_b = (const float*)d_in[2];
    const float* cls_tok = (const float*)d_in[3];
    const float* pos     = (const float*)d_in[4];
    const float* ln1w    = (const float*)d_in[5];
    const float* ln1b    = (const float*)d_in[6];
    const float* qkvw    = (const float*)d_in[7];
    const float* qkvb    = (const float*)d_in[8];
    const float* projw   = (const float*)d_in[9];
    const float* projb   = (const float*)d_in[10];
    const float* ln2w    = (const float*)d_in[11];
    const float* ln2b    = (const float*)d_in[12];
    const float* fc1w    = (const float*)d_in[13];
    const float* fc1b    = (const float*)d_in[14];
    const float* fc2w    = (const float*)d_in[15];
    const float* fc2b    = (const float*)d_in[16];
    const float* normw   = (const float*)d_in[17];
    const float* normb   = (const float*)d_in[18];
    const float* headw   = (const float*)d_in[19];
    const float* headb   = (const float*)d_in[20];
    float* out = (float*)d_out;

    char* ws = (char*)d_ws;
    const size_t MB = 1024ull * 1024ull;
    int*   si   = (int*)ws;                    // si[0]=Nt
    float* sf   = (float*)(ws + 64);
    int*   keep = (int*)(ws + 256);
    float* sabh = (float*)(ws + 4096);         // 384*2 f32
    float* imph = (float*)(ws + 16384);        // 197*384 f32 transposed ~ 303 KB
    unsigned short* xtA = (unsigned short*)(ws + 1 * MB);     // 9.7 MB bf16 residual
    unsigned short* xtB = (unsigned short*)(ws + 12 * MB);    // 9.7 MB bf16 residual
    __hip_bfloat16* obuf = (__hip_bfloat16*)(ws + 23 * MB);   // 9.7 MB attn out
    __hip_bfloat16* qsplit = (__hip_bfloat16*)(ws + 33 * MB); // 29 MB bf16
    __hip_bfloat16* hbuf   = (__hip_bfloat16*)(ws + 33 * MB); // fc1 out (aliases qsplit)
    __hip_bfloat16* wpat = (__hip_bfloat16*)(ws + 110 * MB);
    __hip_bfloat16* wqkv = (__hip_bfloat16*)(ws + 111 * MB);
    __hip_bfloat16* wprj = (__hip_bfloat16*)(ws + 122 * MB);
    __hip_bfloat16* wfc1 = (__hip_bfloat16*)(ws + 126 * MB);
    __hip_bfloat16* wfc2 = (__hip_bfloat16*)(ws + 141 * MB);
    float2* pstats = (float2*)(ws + 156 * MB);                // 12608 rows x 8 x float2

    k_init<<<64, 384, 0, stream>>>(si, sf, cls_tok, pos, xtA, pstats);
    k_cvtall<<<2048, 256, 0, stream>>>(patch_w, qkvw, projw, fc1w, fc2w,
                                       wpat, wqkv, wprj, wfc1, wfc2);

    // patch embed with fused im2col (reads fp32 x directly), bf16 out (+pos), emit stats
    k_mgemm<0, 2, 0, 1><<<8 * 6 * 25, 256, 0, stream>>>(
        (const void*)x, 768, (const unsigned short*)wpat, 768,
        patch_b, xtA, kD, (const void*)pos, (const int*)nullptr,
        (const float*)nullptr, (const float*)nullptr,
        196, 6, 196, (const int*)nullptr, 196,
        (const float2*)nullptr, pstats);

    unsigned short* cur = xtA; unsigned short* oth = xtB;
    for (int l = 0; l < kL; ++l) {
        const float* l1w = ln1w + l * kD;  const float* l1b = ln1b + l * kD;
        const __hip_bfloat16* qw = wqkv + (size_t)l * 1152 * kD;
        const float* qb = qkvb + l * 1152;
        const __hip_bfloat16* pw = wprj + (size_t)l * kD * kD;
        const float* pb = projb + l * kD;
        const float* l2w = ln2w + l * kD;  const float* l2b = ln2b + l * kD;
        const __hip_bfloat16* f1w = wfc1 + (size_t)l * 1536 * kD;
        const float* f1b = fc1b + l * 1536;
        const __hip_bfloat16* f2w = wfc2 + (size_t)l * kD * 1536;
        const float* f2b = fc2b + l * kD;

        // qkv GEMM with fused LN1 (stats from pstats, bf16 A) -> split BF16 q/k/v
        k_mgemm<0, 1, 1, 0><<<8 * 18 * 25, 256, 0, stream>>>(
            (const void*)cur, kD, (const unsigned short*)qw, kD,
            qb, (unsigned short*)qsplit, 1152, (const void*)nullptr, (const int*)nullptr,
            l1w, l1b, 197, 18, kBAND, si, 0,
            (const float2*)pstats, (float2*)nullptr);
        // decision: coalesced producers (transposed imph) + 1-block finalize
        k_decA<<<kB * kH, 256, 0, stream>>>(qsplit, imph, sabh, si);
        k_decB<<<1, 256, 0, stream>>>(si, sf, imph, sabh, keep);
        // attention on pruned tokens
        k_attn2<<<kB * kH, 256, 0, stream>>>(qsplit, obuf, si, keep);
        // proj + pruned bf16 residual (gather via keep), write other buffer, emit stats
        k_mgemm<0, 0, 0, 1><<<8 * 6 * 25, 256, 0, stream>>>(
            (const void*)obuf, kD, (const unsigned short*)pw, kD,
            pb, oth, kD, (const void*)cur, keep,
            (const float*)nullptr, (const float*)nullptr,
            197, 6, kBAND, si, 0,
            (const float2*)nullptr, pstats);
        { unsigned short* tmp = cur; cur = oth; oth = tmp; }
        // fc1 with fused LN2 (stats from pstats, bf16 A) -> bf16 hbuf, gelu
        k_mgemm<1, 0, 1, 0><<<8 * 24 * 25, 256, 0, stream>>>(
            (const void*)cur, kD, (const unsigned short*)f1w, kD,
            f1b, (unsigned short*)hbuf, 1536, (const void*)nullptr, (const int*)nullptr,
            l2w, l2b, 197, 24, kBAND, si, 0,
            (const float2*)pstats, (float2*)nullptr);
        // fc2 + bf16 residual (in place on cur), emit stats for next layer
        k_mgemm<0, 0, 0, 1><<<8 * 6 * 25, 256, 0, stream>>>(
            (const void*)hbuf, 1536, (const unsigned short*)f2w, 1536,
            f2b, cur, kD, (const void*)cur, (const int*)nullptr,
            (const float*)nullptr, (const float*)nullptr,
            197, 6, kBAND, si, 0,
            (const float2*)nullptr, pstats);
    }

    k_head<<<kB * 4, 256, 0, stream>>>(cur, normw, normb, headw, headb, out);
}

// Round 15
// 1157.175 us; speedup vs baseline: 1.0306x; 1.0306x over previous
//
#include <hip/hip_runtime.h>
#include <hip/hip_bf16.h>

// ---------------- constants ----------------
static constexpr int kL = 12;
static constexpr int kD = 384;
static constexpr int kH = 6;
static constexpr int kB = 64;
static constexpr int kNP = 196;      // patches
static constexpr int kBAND = 197;    // tokens incl cls (max)
static constexpr int kNCLS = 1000;
static constexpr float kSCALE = 0.125f;   // 64^-0.5
static constexpr float kEPS = 1e-6f;
static constexpr size_t kWQ = (size_t)kB * kH * kBAND * 64;   // per-tensor elems in split qkv
static constexpr int kBH = kB * kH;                            // 384

typedef __attribute__((ext_vector_type(8))) short short8;
typedef __attribute__((ext_vector_type(4))) float f32x4;

__device__ __forceinline__ float gelu_f(float x) {
    return 0.5f * x * (1.0f + erff(x * 0.70710678118654752440f));
}
__device__ __forceinline__ unsigned short f2bf(float x) {
    __hip_bfloat16 h = __float2bfloat16(x);
    return *(unsigned short*)&h;
}
__device__ __forceinline__ float bf2f(unsigned short u) {
    unsigned int x = ((unsigned int)u) << 16;
    return __uint_as_float(x);
}

// ---------------- init: state + cls rows of xtA (bf16) + cls-row LN partials ----------------
__global__ __launch_bounds__(384) void k_init(int* si, float* sf,
                                              const float* __restrict__ cls,
                                              const float* __restrict__ pos,
                                              unsigned short* __restrict__ xtA,
                                              float2* __restrict__ pstats) {
    int b = blockIdx.x, c = threadIdx.x;
    unsigned short hv = f2bf(cls[c] + pos[c]);
    xtA[(size_t)b * kBAND * kD + c] = hv;
    float v = bf2f(hv);                      // stats of the ROUNDED value
    __shared__ float r1[384], r2[384];
    r1[c] = v; r2[c] = v * v;
    __syncthreads();
    if (c < 128) { r1[c] += r1[c + 128] + r1[c + 256]; r2[c] += r2[c + 128] + r2[c + 256]; }
    __syncthreads();
    for (int st = 64; st; st >>= 1) {
        if (c < st) { r1[c] += r1[c + st]; r2[c] += r2[c + st]; }
        __syncthreads();
    }
    if (c == 0) {
        pstats[(size_t)(b * kBAND) * 8 + 0] = make_float2(r1[0], r2[0]);
#pragma unroll
        for (int nn = 1; nn < 6; ++nn) pstats[(size_t)(b * kBAND) * 8 + nn] = make_float2(0.f, 0.f);
        if (b == 0) { si[0] = kBAND; sf[0] = 1.0f; }
    }
}

// ---------------- fp32 -> bf16 weight conversion; fold LN gamma into qkvw/fc1w ------------
__global__ __launch_bounds__(256) void k_cvtall(
    const float* __restrict__ s0, const float* __restrict__ s1, const float* __restrict__ s2,
    const float* __restrict__ s3, const float* __restrict__ s4,
    const float* __restrict__ lw1, const float* __restrict__ lw2,
    __hip_bfloat16* __restrict__ d0, __hip_bfloat16* __restrict__ d1, __hip_bfloat16* __restrict__ d2,
    __hip_bfloat16* __restrict__ d3, __hip_bfloat16* __restrict__ d4) {
    const int c0 = 73728, c1 = 1400832, c2 = 1843200, c3 = 3612672, c4 = 5382144;
    int stride = gridDim.x * 256;
    for (int i = blockIdx.x * 256 + threadIdx.x; i < c4; i += stride) {
        const float* src; __hip_bfloat16* dst; int off; int fold = 0;
        const float* lw = nullptr; int perL = 0;
        if (i < c0)      { src = s0; dst = d0; off = i; }
        else if (i < c1) { src = s1; dst = d1; off = i - c0; fold = 1; lw = lw1; perL = 442368; }
        else if (i < c2) { src = s2; dst = d2; off = i - c1; }
        else if (i < c3) { src = s3; dst = d3; off = i - c2; fold = 1; lw = lw2; perL = 589824; }
        else             { src = s4; dst = d4; off = i - c3; }
        float4 v = ((const float4*)src)[off];
        if (fold) {
            int f0 = off << 2;
            int l = f0 / perL;
            int k = f0 % 384;
            float4 g = *(const float4*)(lw + l * 384 + k);
            v.x *= g.x; v.y *= g.y; v.z *= g.z; v.w *= g.w;
        }
        dst[4 * off + 0] = __float2bfloat16(v.x);
        dst[4 * off + 1] = __float2bfloat16(v.y);
        dst[4 * off + 2] = __float2bfloat16(v.z);
        dst[4 * off + 3] = __float2bfloat16(v.w);
    }
}

// ---------------- LN-fold per-column coefficients: G = sum(bf16(gW)), Bn = sum(lnb*W) ------
__global__ __launch_bounds__(256) void k_lncoef(
    const unsigned short* __restrict__ wq, const float* __restrict__ qkvw_f, const float* __restrict__ ln1b,
    const unsigned short* __restrict__ wf, const float* __restrict__ fc1w_f, const float* __restrict__ ln2b,
    float2* __restrict__ qcoef, float2* __restrict__ fcoef) {
    const int NQ = kL * 1152;
    const int NF = kL * 1536;
    int col = blockIdx.x * 4 + (threadIdx.x >> 6);
    int lane = threadIdx.x & 63;
    if (col >= NQ + NF) return;
    bool isQ = col < NQ;
    int c = isQ ? col : col - NQ;
    int l = c / (isQ ? 1152 : 1536);
    const unsigned short* w = (isQ ? wq : wf) + (size_t)c * 384;
    const float* wo = (isQ ? qkvw_f : fc1w_f) + (size_t)c * 384;
    const float* lb = (isQ ? ln1b : ln2b) + l * 384;
    float g = 0.f, bn = 0.f;
#pragma unroll
    for (int e = 0; e < 6; ++e) {
        int k = lane + (e << 6);
        g += bf2f(w[k]);
        bn += lb[k] * wo[k];
    }
#pragma unroll
    for (int off = 1; off < 64; off <<= 1) { g += __shfl_xor(g, off, 64); bn += __shfl_xor(bn, off, 64); }
    if (lane == 0) { if (isQ) qcoef[c] = make_float2(g, bn); else fcoef[c] = make_float2(g, bn); }
}

// ---------------- bf16 MFMA GEMM: 64x64 block tile (proven geometry) ----------------
// XCD-pinned 1-D grid: L -> (xcd=L&7, n=(L>>3)%nT, r=((L>>3)/nT)*8+xcd).
// Virtual row compaction: rv in [0,64*Nt) -> (b=rv/Nt, t=rv%Nt), phys row b*band+t.
// Residual stream is BF16 everywhere.
// LNA==1: LN folded into weights; plain bf16 A staging; epilogue applies
//         v = rs*acc + bias + Bn - mu*rs*G with per-row (mu,rs) from pstatsIn and
//         per-col (G,Bn) from lncoef.
// STATS==1: store pass emits per-(row, 64-col-slice) (sum,sumsq) of ROUNDED stores.
// MODE: 0 normal (R bf16 residual, keepR gather), 1 qkv head-split store,
//       2 patch: A on-the-fly from fp32 image (im2col fused), +patch_b, +pos(fp32), row t+1.
template<int ACT_GELU, int MODE, int LNA, int STATS>
__global__ __launch_bounds__(256) void k_mgemm(
    const void* __restrict__ Av, int lda,
    const unsigned short* __restrict__ W, int K,
    const float* __restrict__ bias,
    unsigned short* __restrict__ Cv, int ldc,
    const void* __restrict__ Rv,
    const int* __restrict__ keepR,
    const float2* __restrict__ lncoef,
    int rT, int nT, int band,
    const int* __restrict__ NtPtr, int ntConst,
    const float2* __restrict__ pstatsIn, float2* __restrict__ pstatsOut)
{
    __shared__ __align__(16) unsigned char pool[18432];
    unsigned short (*As)[72] = (unsigned short (*)[72])pool;
    unsigned short (*Ws)[72] = (unsigned short (*)[72])(pool + 9216);
    unsigned short (*Cu)[76] = (unsigned short (*)[76])pool;   // 64x76 u16 overlay
    __shared__ float mus[64], rss[64];

    int Nt = NtPtr ? NtPtr[0] : ntConst;
    unsigned int rowsTotal = (unsigned int)kB * (unsigned int)Nt;

    int L = blockIdx.x;
    int xcd = L & 7;
    int m = L >> 3;
    int n = m % nT;
    int r = (m / nT) * 8 + xcd;
    if (r >= rT) return;
    unsigned int r0 = (unsigned int)r * 64;
    int n0 = n * 64;
    if (r0 >= rowsTotal) return;

    const float* Rf = (const float*)Rv;                    // MODE 2: pos (fp32)
    const unsigned short* Rb = (const unsigned short*)Rv;  // MODE 0: residual (bf16)

    int tid = threadIdx.x;
    int srow = tid >> 3;            // 0..31
    int scol = (tid & 7) << 3;      // 0..56 step 8

    unsigned int rv0 = r0 + srow, rv1 = r0 + srow + 32;
    bool v0 = rv0 < rowsTotal, v1 = rv1 < rowsTotal;
    const unsigned short* ah0 = nullptr; const unsigned short* ah1 = nullptr;
    const float* xb0 = nullptr; const float* xb1 = nullptr;   // MODE 2 image bases
    if (MODE == 2) {
        if (v0) {
            unsigned int bb = rv0 / (unsigned int)Nt, tt = rv0 - bb * Nt;
            int py = tt / 14, px = tt - py * 14;
            xb0 = (const float*)Av + (size_t)bb * 3 * 224 * 224 + (py * 16) * 224 + px * 16;
        }
        if (v1) {
            unsigned int bb = rv1 / (unsigned int)Nt, tt = rv1 - bb * Nt;
            int py = tt / 14, px = tt - py * 14;
            xb1 = (const float*)Av + (size_t)bb * 3 * 224 * 224 + (py * 16) * 224 + px * 16;
        }
    } else {
        if (v0) {
            unsigned int bb = rv0 / (unsigned int)Nt, tt = rv0 - bb * Nt;
            ah0 = (const unsigned short*)Av + ((size_t)bb * band + tt) * lda;
        }
        if (v1) {
            unsigned int bb = rv1 / (unsigned int)Nt, tt = rv1 - bb * Nt;
            ah1 = (const unsigned short*)Av + ((size_t)bb * band + tt) * lda;
        }
    }
    const unsigned short* wp0 = W + (size_t)(n0 + srow) * K;
    const unsigned short* wp1 = W + (size_t)(n0 + srow + 32) * K;

    if (LNA) {
        if (tid < 64) {
            unsigned int rv = r0 + tid;
            float mu = 0.f, rsd = 0.f;
            if (rv < rowsTotal) {
                unsigned int bb = rv / (unsigned int)Nt, tt = rv - bb * Nt;
                const float2* ps = pstatsIn + ((size_t)bb * band + tt) * 8;
                float s1 = 0.f, s2 = 0.f;
#pragma unroll
                for (int nn = 0; nn < 6; ++nn) { float2 p = ps[nn]; s1 += p.x; s2 += p.y; }
                mu = s1 * (1.f / 384.f);
                float var = fmaxf(s2 * (1.f / 384.f) - mu * mu, 0.f);
                rsd = rsqrtf(var + kEPS);
            }
            mus[tid] = mu; rss[tid] = rsd;
        }
        __syncthreads();
    }

    int wave = tid >> 6, lane = tid & 63;
    int wr32 = ((wave >> 1) & 1) * 32, wc32 = (wave & 1) * 32;
    int l15 = lane & 15, l4 = lane >> 4;

    f32x4 acc00 = {}, acc01 = {}, acc10 = {}, acc11 = {};

    for (int k0 = 0; k0 < K; k0 += 64) {
        uint4 zero = make_uint4(0, 0, 0, 0);
        uint4 a0 = zero, a1 = zero;
        uint4 w0 = *(const uint4*)(wp0 + k0 + scol);
        uint4 w1 = *(const uint4*)(wp1 + k0 + scol);
        if (MODE == 2) {
            int k = k0 + scol;
            int c = k >> 8;
            int rr_ = k & 255;
            int ky = rr_ >> 4, kx = rr_ & 15;
            size_t off = (size_t)c * 50176 + (size_t)ky * 224 + kx;
            if (v0) {
                float4 x0 = *(const float4*)(xb0 + off);
                float4 x1 = *(const float4*)(xb0 + off + 4);
                unsigned short p[8];
                p[0] = f2bf(x0.x); p[1] = f2bf(x0.y); p[2] = f2bf(x0.z); p[3] = f2bf(x0.w);
                p[4] = f2bf(x1.x); p[5] = f2bf(x1.y); p[6] = f2bf(x1.z); p[7] = f2bf(x1.w);
                a0 = *(uint4*)p;
            }
            if (v1) {
                float4 x0 = *(const float4*)(xb1 + off);
                float4 x1 = *(const float4*)(xb1 + off + 4);
                unsigned short p[8];
                p[0] = f2bf(x0.x); p[1] = f2bf(x0.y); p[2] = f2bf(x0.z); p[3] = f2bf(x0.w);
                p[4] = f2bf(x1.x); p[5] = f2bf(x1.y); p[6] = f2bf(x1.z); p[7] = f2bf(x1.w);
                a1 = *(uint4*)p;
            }
        } else {
            a0 = v0 ? *(const uint4*)(ah0 + k0 + scol) : zero;
            a1 = v1 ? *(const uint4*)(ah1 + k0 + scol) : zero;
        }
        __syncthreads();
        *(uint4*)&As[srow][scol] = a0;
        *(uint4*)&As[srow + 32][scol] = a1;
        *(uint4*)&Ws[srow][scol] = w0;
        *(uint4*)&Ws[srow + 32][scol] = w1;
        __syncthreads();
#pragma unroll
        for (int ks = 0; ks < 2; ++ks) {
            short8 af_0 = *(const short8*)&As[wr32 + l15][ks * 32 + l4 * 8];
            short8 af_1 = *(const short8*)&As[wr32 + 16 + l15][ks * 32 + l4 * 8];
            short8 bf_0 = *(const short8*)&Ws[wc32 + l15][ks * 32 + l4 * 8];
            short8 bf_1 = *(const short8*)&Ws[wc32 + 16 + l15][ks * 32 + l4 * 8];
            acc00 = __builtin_amdgcn_mfma_f32_16x16x32_bf16(af_0, bf_0, acc00, 0, 0, 0);
            acc01 = __builtin_amdgcn_mfma_f32_16x16x32_bf16(af_0, bf_1, acc01, 0, 0, 0);
            acc10 = __builtin_amdgcn_mfma_f32_16x16x32_bf16(af_1, bf_0, acc10, 0, 0, 0);
            acc11 = __builtin_amdgcn_mfma_f32_16x16x32_bf16(af_1, bf_1, acc11, 0, 0, 0);
        }
    }

    // -------- epilogue: LN-fold / bias / act / residual, stage bf16 tile in LDS --------
    __syncthreads();
    f32x4 accs[2][2] = { { acc00, acc01 }, { acc10, acc11 } };
#pragma unroll
    for (int fi = 0; fi < 2; ++fi) {
        int lrow = wr32 + fi * 16 + l4 * 4;
        unsigned int rvb = r0 + lrow;
#pragma unroll
        for (int fj = 0; fj < 2; ++fj) {
            int lcol = wc32 + fj * 16 + l15;
            float bv = bias ? bias[n0 + lcol] : 0.f;
            float2 cf = make_float2(0.f, 0.f);
            if (LNA) cf = lncoef[n0 + lcol];
#pragma unroll
            for (int rr = 0; rr < 4; ++rr) {
                unsigned int rv = rvb + rr;
                float v;
                if (LNA) {
                    float muv = mus[lrow + rr], rsv = rss[lrow + rr];
                    v = accs[fi][fj][rr] * rsv + bv + cf.y - muv * rsv * cf.x;
                } else {
                    v = accs[fi][fj][rr] + bv;
                }
                if (ACT_GELU) v = gelu_f(v);
                if (MODE == 2) {
                    if (rv < rowsTotal) {
                        unsigned int bb = rv / (unsigned int)Nt;
                        unsigned int tt = rv - bb * (unsigned int)Nt;
                        v += Rf[(size_t)(tt + 1) * kD + n0 + lcol];
                    }
                } else if (Rv && rv < rowsTotal) {
                    unsigned int bb = rv / (unsigned int)Nt;
                    unsigned int tt = rv - bb * (unsigned int)Nt;
                    size_t rrow = keepR ? ((size_t)bb * band + keepR[tt]) : ((size_t)bb * band + tt);
                    v += bf2f(Rb[rrow * ldc + n0 + lcol]);
                }
                Cu[lrow + rr][lcol] = f2bf(v);
            }
        }
    }
    __syncthreads();

    // -------- coalesced stores (+ optional LN partial-stats emit) --------
#pragma unroll
    for (int i = 0; i < 2; ++i) {
        int id = tid + (i << 8);
        int row = id >> 3, c2 = id & 7;
        unsigned int rv = r0 + row;
        if (rv < rowsTotal) {
            unsigned int bb = rv / (unsigned int)Nt;
            unsigned int tt = rv - bb * (unsigned int)Nt;
            uint4 val = *(const uint4*)&Cu[row][c2 << 3];
            if (MODE == 1) {
                int which = n0 >= 768 ? 2 : (n0 >= 384 ? 1 : 0);
                int hh = (n0 - which * 384) >> 6;
                *(uint4*)(Cv + (size_t)which * kWQ +
                          (((size_t)bb * kH + hh) * kBAND + tt) * 64 + ((n0 & 63) + (c2 << 3))) = val;
            } else if (MODE == 2) {
                *(uint4*)(Cv + ((size_t)bb * kBAND + tt + 1) * ldc + n0 + (c2 << 3)) = val;
            } else {
                *(uint4*)(Cv + ((size_t)bb * band + tt) * ldc + n0 + (c2 << 3)) = val;
            }
            if (STATS) {
                const unsigned short* u = (const unsigned short*)&val;
                float s1 = 0.f, s2 = 0.f;
#pragma unroll
                for (int e = 0; e < 8; ++e) { float f = bf2f(u[e]); s1 += f; s2 += f * f; }
#pragma unroll
                for (int off = 1; off < 8; off <<= 1) {
                    s1 += __shfl_xor(s1, off, 64);
                    s2 += __shfl_xor(s2, off, 64);
                }
                if (c2 == 0) {
                    size_t sridx = (MODE == 2) ? ((size_t)bb * kBAND + tt + 1)
                                               : ((size_t)bb * band + tt);
                    pstatsOut[sridx * 8 + n] = make_float2(s1, s2);
                }
            }
        }
    }
}

// ---------------- decision A: per-(b,h) importance; imph stored TRANSPOSED [token][bh] ------
__global__ __launch_bounds__(256) void k_decA(const __hip_bfloat16* __restrict__ qsplit,
                                              float* __restrict__ imph, float* __restrict__ sabh,
                                              const int* __restrict__ si) {
    int Nt = si[0];
    if (Nt - 1 <= 16) return;
    int tid = threadIdx.x, w = tid >> 6, lane = tid & 63;
    int bh = blockIdx.x;
    __shared__ float qs[64];
    __shared__ float sdot[224], svn[224];
    __shared__ float red[256];
    const __hip_bfloat16* qp = qsplit + (size_t)bh * kBAND * 64;
    const __hip_bfloat16* kp = qsplit + kWQ + (size_t)bh * kBAND * 64;
    const __hip_bfloat16* vp = qsplit + 2 * kWQ + (size_t)bh * kBAND * 64;
    if (tid < 64) qs[tid] = __bfloat162float(qp[tid]);   // cls q
    __syncthreads();
    float qv = qs[lane];
    for (int j = w; j < Nt; j += 8) {
        int j2 = j + 4;
        bool has2 = j2 < Nt;
        float k1 = __bfloat162float(kp[(size_t)j * 64 + lane]);
        float v1 = __bfloat162float(vp[(size_t)j * 64 + lane]);
        float k2 = has2 ? __bfloat162float(kp[(size_t)j2 * 64 + lane]) : 0.f;
        float v2 = has2 ? __bfloat162float(vp[(size_t)j2 * 64 + lane]) : 0.f;
        float p1 = qv * k1, n1 = v1 * v1;
        float p2 = qv * k2, n2 = v2 * v2;
#pragma unroll
        for (int off = 1; off < 64; off <<= 1) {
            p1 += __shfl_xor(p1, off, 64); n1 += __shfl_xor(n1, off, 64);
            p2 += __shfl_xor(p2, off, 64); n2 += __shfl_xor(n2, off, 64);
        }
        if (lane == 0) {
            sdot[j] = p1 * kSCALE; svn[j] = sqrtf(n1);
            if (has2) { sdot[j2] = p2 * kSCALE; svn[j2] = sqrtf(n2); }
        }
    }
    __syncthreads();
    float s = (tid < Nt) ? sdot[tid] : -INFINITY;
    red[tid] = s; __syncthreads();
    for (int st = 128; st; st >>= 1) { if (tid < st) red[tid] = fmaxf(red[tid], red[tid + st]); __syncthreads(); }
    float mmax = red[0]; __syncthreads();
    float e = (tid < Nt) ? expf(s - mmax) : 0.f;
    red[tid] = e; __syncthreads();
    for (int st = 128; st; st >>= 1) { if (tid < st) red[tid] += red[tid + st]; __syncthreads(); }
    float inv = 1.f / red[0];
    float val = (tid < Nt) ? e * inv * svn[tid] : 0.f;
    if (tid < Nt) imph[(size_t)tid * kBH + bh] = val;    // transposed
    __syncthreads();
    red[tid] = val; __syncthreads();
    for (int st = 128; st; st >>= 1) { if (tid < st) red[tid] += red[tid + st]; __syncthreads(); }
    if (tid == 0) { sabh[2 * bh] = red[0]; sabh[2 * bh + 1] = val; }   // tid0 val = token 0
}

// ---------------- decision B: finalize (1 block): mass/ratio, top-k, keep, commit Nt --------
__global__ __launch_bounds__(256) void k_decB(int* __restrict__ si, float* __restrict__ sf,
                                              const float* __restrict__ imph,
                                              const float* __restrict__ sabh,
                                              int* __restrict__ keep) {
    int Nt = si[0];
    int tid = threadIdx.x;
    if (Nt - 1 <= 16) {
        for (int j = tid; j < Nt; j += 256) keep[j] = j;
        return;
    }
    int N = Nt - 1;
    __shared__ float red[256];
    float v = 0.f;
    if (tid < kB) {
        float sa = 0.f, i0 = 0.f;
#pragma unroll
        for (int hh = 0; hh < kH; ++hh) {
            sa += sabh[2 * (tid * kH + hh)];
            i0 += sabh[2 * (tid * kH + hh) + 1];
        }
        sa *= (1.f / 6.f); i0 *= (1.f / 6.f);
        v = (sa - i0) / (sa + kEPS);
    }
    red[tid] = v; __syncthreads();
    for (int st = 128; st; st >>= 1) { if (tid < st) red[tid] += red[tid + st]; __syncthreads(); }
    float mass = red[0] * (1.f / 64.f);
    float prev = sf[0];
    float ratio = 0.5f * mass / (prev + kEPS);
    ratio = fminf(fmaxf(ratio, 0.f), 1.f);
    int N_next = (int)((double)N * (double)ratio);
    if (N_next < 16) N_next = 16;
    if (tid == 0) sf[0] = mass;
    __syncthreads();
    if (N_next >= N) {
        for (int j = tid; j < Nt; j += 256) keep[j] = j;
        return;
    }
    __shared__ float scq[200][4];
    __shared__ float sc[200];
    __shared__ int flag[200];
    for (int task = tid; task < N * 4; task += 256) {
        int row = task >> 2, seg = task & 3;
        const float4* p = (const float4*)(imph + (size_t)(row + 1) * kBH) + seg * 24;
        float a0 = 0.f, a1 = 0.f, a2 = 0.f, a3 = 0.f;
#pragma unroll
        for (int q = 0; q < 24; q += 4) {
            float4 x0 = p[q + 0], x1 = p[q + 1], x2 = p[q + 2], x3 = p[q + 3];
            a0 += (x0.x + x0.y) + (x0.z + x0.w);
            a1 += (x1.x + x1.y) + (x1.z + x1.w);
            a2 += (x2.x + x2.y) + (x2.z + x2.w);
            a3 += (x3.x + x3.y) + (x3.z + x3.w);
        }
        scq[row][seg] = (a0 + a1) + (a2 + a3);
    }
    __syncthreads();
    if (tid < N) sc[tid] = (scq[tid][0] + scq[tid][1]) + (scq[tid][2] + scq[tid][3]);
    __syncthreads();
    if (tid < N) {
        float s2 = sc[tid];
        int rank = 0;
        for (int i = 0; i < N; ++i) {
            float o2 = sc[i];
            rank += (o2 > s2) || (o2 == s2 && i < tid);
        }
        flag[tid] = (rank < N_next) ? 1 : 0;
    }
    __syncthreads();
    if (tid == 0) {
        keep[0] = 0;
        int pos = 1;
        for (int j = 0; j < N; ++j) if (flag[j]) keep[pos++] = j + 1;
        si[0] = N_next + 1;
    }
}

// ---------------- MFMA flash attention: one block per (b,h) (bf16 qsplit) ----------------
__global__ __launch_bounds__(256) void k_attn2(const __hip_bfloat16* __restrict__ qsplit,
                                               __hip_bfloat16* __restrict__ o,
                                               const int* __restrict__ si,
                                               const int* __restrict__ keep) {
    __shared__ __align__(16) unsigned short Kb[224][72];
    __shared__ __align__(16) unsigned short Vt[64][228];
    __shared__ __align__(16) unsigned short Pb[4][16][228];
    int Nt = si[0];
    int bh = blockIdx.x;
    int b = bh / kH, h = bh - b * kH;
    int tid = threadIdx.x, w = tid >> 6, lane = tid & 63;
    int l15 = lane & 15, l4 = lane >> 4;
    int nJT = (Nt + 15) >> 4;
    int nKT = (Nt + 31) >> 5;
    int NTP = nKT << 5;

    const unsigned short* qb = (const unsigned short*)qsplit + (size_t)bh * kBAND * 64;
    const unsigned short* kb = (const unsigned short*)qsplit + kWQ + (size_t)bh * kBAND * 64;
    const unsigned short* vb = (const unsigned short*)qsplit + 2 * kWQ + (size_t)bh * kBAND * 64;

    {
        int rr = tid >> 3;
        int c8 = (tid & 7) << 3;
        for (int r = rr; r < NTP; r += 32) {
            uint4 kv = make_uint4(0, 0, 0, 0), vv = make_uint4(0, 0, 0, 0);
            if (r < Nt) {
                int old = keep[r];
                kv = *(const uint4*)(kb + ((size_t)old << 6) + c8);
                vv = *(const uint4*)(vb + ((size_t)old << 6) + c8);
            }
            *(uint4*)&Kb[r][c8] = kv;
            const unsigned short* vs = (const unsigned short*)&vv;
#pragma unroll
            for (int e = 0; e < 8; ++e) Vt[c8 + e][r] = vs[e];
        }
    }
    __syncthreads();

    for (int strip = w; strip < nJT; strip += 4) {
        int tq = (strip << 4) + l15;
        int told = (tq < Nt) ? keep[tq] : 0;
        const unsigned short* qrow = qb + ((size_t)told << 6) + (l4 << 3);
        short8 qf0 = *(const short8*)(qrow);
        short8 qf1 = *(const short8*)(qrow + 32);

        f32x4 sv[13];
#pragma unroll
        for (int jt = 0; jt < 13; ++jt) {
            if (jt < nJT) {
                const unsigned short* kr = &Kb[(jt << 4) + l15][l4 << 3];
                short8 kf0 = *(const short8*)(kr);
                short8 kf1 = *(const short8*)(kr + 32);
                f32x4 a = {};
                a = __builtin_amdgcn_mfma_f32_16x16x32_bf16(qf0, kf0, a, 0, 0, 0);
                a = __builtin_amdgcn_mfma_f32_16x16x32_bf16(qf1, kf1, a, 0, 0, 0);
                sv[jt] = a;
            }
        }
        float mx[4] = { -INFINITY, -INFINITY, -INFINITY, -INFINITY };
#pragma unroll
        for (int jt = 0; jt < 13; ++jt) if (jt < nJT) {
            bool ok = ((jt << 4) + l15) < Nt;
#pragma unroll
            for (int r = 0; r < 4; ++r) {
                float s = ok ? sv[jt][r] * kSCALE : -INFINITY;
                sv[jt][r] = s;
                mx[r] = fmaxf(mx[r], s);
            }
        }
#pragma unroll
        for (int r = 0; r < 4; ++r) {
            mx[r] = fmaxf(mx[r], __shfl_xor(mx[r], 1, 64));
            mx[r] = fmaxf(mx[r], __shfl_xor(mx[r], 2, 64));
            mx[r] = fmaxf(mx[r], __shfl_xor(mx[r], 4, 64));
            mx[r] = fmaxf(mx[r], __shfl_xor(mx[r], 8, 64));
        }
        float sm[4] = { 0.f, 0.f, 0.f, 0.f };
#pragma unroll
        for (int jt = 0; jt < 13; ++jt) if (jt < nJT) {
#pragma unroll
            for (int r = 0; r < 4; ++r) {
                float p = expf(sv[jt][r] - mx[r]);
                sv[jt][r] = p;
                sm[r] += p;
            }
        }
#pragma unroll
        for (int r = 0; r < 4; ++r) {
            sm[r] += __shfl_xor(sm[r], 1, 64);
            sm[r] += __shfl_xor(sm[r], 2, 64);
            sm[r] += __shfl_xor(sm[r], 4, 64);
            sm[r] += __shfl_xor(sm[r], 8, 64);
            sm[r] = 1.f / sm[r];
        }
#pragma unroll
        for (int jt = 0; jt < 13; ++jt) if (jt < nJT) {
#pragma unroll
            for (int r = 0; r < 4; ++r)
                Pb[w][(l4 << 2) + r][(jt << 4) + l15] = f2bf(sv[jt][r] * sm[r]);
        }
        for (int c = (nJT << 4) + lane; c < NTP; c += 64) {
#pragma unroll
            for (int rr2 = 0; rr2 < 16; ++rr2) Pb[w][rr2][c] = 0;
        }
        asm volatile("s_waitcnt lgkmcnt(0)" ::: "memory");
        __builtin_amdgcn_sched_barrier(0);

        f32x4 oacc[4] = { {}, {}, {}, {} };
#pragma unroll
        for (int kt = 0; kt < 7; ++kt) if (kt < nKT) {
            short8 pf = *(const short8*)&Pb[w][l15][(kt << 5) + (l4 << 3)];
#pragma unroll
            for (int dt = 0; dt < 4; ++dt) {
                short8 vf = *(const short8*)&Vt[(dt << 4) + l15][(kt << 5) + (l4 << 3)];
                oacc[dt] = __builtin_amdgcn_mfma_f32_16x16x32_bf16(pf, vf, oacc[dt], 0, 0, 0);
            }
        }
#pragma unroll
        for (int dt = 0; dt < 4; ++dt) {
#pragma unroll
            for (int r = 0; r < 4; ++r) {
                int tqo = (strip << 4) + (l4 << 2) + r;
                if (tqo < Nt)
                    o[((size_t)b * kBAND + tqo) * kD + h * 64 + (dt << 4) + l15] =
                        __float2bfloat16(oacc[dt][r]);
            }
        }
    }
}

// ---------------- head with fused final LayerNorm (bf16 residual in) ----------------
__global__ __launch_bounds__(256) void k_head(const unsigned short* __restrict__ X,
                                              const float* __restrict__ nw, const float* __restrict__ nb,
                                              const float* __restrict__ hw, const float* __restrict__ hb,
                                              float* __restrict__ out) {
    int b = blockIdx.x >> 2;
    int tid = threadIdx.x;
    __shared__ float xs[384];
    __shared__ float red[256];
    const unsigned short* row = X + (size_t)b * kBAND * kD;
    float s1 = 0.f, s2 = 0.f;
    for (int c = tid; c < 384; c += 256) { float v = bf2f(row[c]); xs[c] = v; s1 += v; s2 += v * v; }
    red[tid] = s1; __syncthreads();
    for (int st = 128; st; st >>= 1) { if (tid < st) red[tid] += red[tid + st]; __syncthreads(); }
    float sum = red[0]; __syncthreads();
    red[tid] = s2; __syncthreads();
    for (int st = 128; st; st >>= 1) { if (tid < st) red[tid] += red[tid + st]; __syncthreads(); }
    float sq = red[0];
    float mu = sum * (1.f / 384.f);
    float var = fmaxf(sq * (1.f / 384.f) - mu * mu, 0.f);
    float rs = rsqrtf(var + kEPS);
    __syncthreads();
    for (int c = tid; c < 384; c += 256) xs[c] = (xs[c] - mu) * rs * nw[c] + nb[c];
    __syncthreads();
    int n = ((blockIdx.x & 3) << 8) + tid;
    if (n >= kNCLS) return;
    const float* wrow = hw + (size_t)n * kD;
    float acc = 0.f;
#pragma unroll 8
    for (int d = 0; d < kD; d += 4) {
        float4 w4 = *(const float4*)(wrow + d);
        acc += xs[d] * w4.x + xs[d + 1] * w4.y + xs[d + 2] * w4.z + xs[d + 3] * w4.w;
    }
    out[(size_t)b * kNCLS + n] = acc + hb[n];
}

// ---------------- host launch ----------------
extern "C" void kernel_launch(void* const* d_in, const int* in_sizes, int n_in,
                              void* d_out, int out_size, void* d_ws, size_t ws_size,
                              hipStream_t stream) {
    const float* x       = (const float*)d_in[0];
    const float* patch_w = (const float*)d_in[1];
    const float* patch_b = (const float*)d_in[2];
    const float* cls_tok = (const float*)d_in[3];
    const float* pos     = (const float*)d_in[4];
    const float* ln1w    = (const float*)d_in[5];
    const float* ln1b    = (const float*)d_in[6];
    const float* qkvw    = (const float*)d_in[7];
    const float* qkvb    = (const float*)d_in[8];
    const float* projw   = (const float*)d_in[9];
    const float* projb   = (const float*)d_in[10];
    const float* ln2w    = (const float*)d_in[11];
    const float* ln2b    = (const float*)d_in[12];
    const float* fc1w    = (const float*)d_in[13];
    const float* fc1b    = (const float*)d_in[14];
    const float* fc2w    = (const float*)d_in[15];
    const float* fc2b    = (const float*)d_in[16];
    const float* normw   = (const float*)d_in[17];
    const float* normb   = (const float*)d_in[18];
    const float* headw   = (const float*)d_in[19];
    const float* headb   = (const float*)d_in[20];
    float* out = (float*)d_out;

    char* ws = (char*)d_ws;
    const size_t MB = 1024ull * 1024ull;
    int*   si   = (int*)ws;                    // si[0]=Nt
    float* sf   = (float*)(ws + 64);
    int*   keep = (int*)(ws + 256);
    float* sabh = (float*)(ws + 4096);         // 384*2 f32
    float* imph = (float*)(ws + 16384);        // 197*384 f32 transposed ~ 303 KB
    unsigned short* xtA = (unsigned short*)(ws + 1 * MB);     // 9.7 MB bf16 residual
    unsigned short* xtB = (unsigned short*)(ws + 12 * MB);    // 9.7 MB bf16 residual
    __hip_bfloat16* obuf = (__hip_bfloat16*)(ws + 23 * MB);   // 9.7 MB attn out
    __hip_bfloat16* qsplit = (__hip_bfloat16*)(ws + 33 * MB); // 29 MB bf16
    __hip_bfloat16* hbuf   = (__hip_bfloat16*)(ws + 33 * MB); // fc1 out (aliases qsplit)
    __hip_bfloat16* wpat = (__hip_bfloat16*)(ws + 110 * MB);
    __hip_bfloat16* wqkv = (__hip_bfloat16*)(ws + 111 * MB);
    __hip_bfloat16* wprj = (__hip_bfloat16*)(ws + 122 * MB);
    __hip_bfloat16* wfc1 = (__hip_bfloat16*)(ws + 126 * MB);
    __hip_bfloat16* wfc2 = (__hip_bfloat16*)(ws + 141 * MB);
    float2* pstats = (float2*)(ws + 156 * MB);                // 12608 rows x 8 x float2
    float2* qcoef  = (float2*)(ws + 158 * MB);                // 12*1152 float2 ~110 KB
    float2* fcoef  = (float2*)(ws + 159 * MB);                // 12*1536 float2 ~148 KB

    k_init<<<64, 384, 0, stream>>>(si, sf, cls_tok, pos, xtA, pstats);
    k_cvtall<<<2048, 256, 0, stream>>>(patch_w, qkvw, projw, fc1w, fc2w,
                                       ln1w, ln2w,
                                       wpat, wqkv, wprj, wfc1, wfc2);
    k_lncoef<<<8064, 256, 0, stream>>>((const unsigned short*)wqkv, qkvw, ln1b,
                                       (const unsigned short*)wfc1, fc1w, ln2b,
                                       qcoef, fcoef);

    // patch embed with fused im2col (reads fp32 x directly), bf16 out (+pos), emit stats
    k_mgemm<0, 2, 0, 1><<<8 * 6 * 25, 256, 0, stream>>>(
        (const void*)x, 768, (const unsigned short*)wpat, 768,
        patch_b, xtA, kD, (const void*)pos, (const int*)nullptr,
        (const float2*)nullptr,
        196, 6, 196, (const int*)nullptr, 196,
        (const float2*)nullptr, pstats);

    unsigned short* cur = xtA; unsigned short* oth = xtB;
    for (int l = 0; l < kL; ++l) {
        const __hip_bfloat16* qw = wqkv + (size_t)l * 1152 * kD;
        const float* qb = qkvb + l * 1152;
        const __hip_bfloat16* pw = wprj + (size_t)l * kD * kD;
        const float* pb = projb + l * kD;
        const __hip_bfloat16* f1w = wfc1 + (size_t)l * 1536 * kD;
        const float* f1b = fc1b + l * 1536;
        const __hip_bfloat16* f2w = wfc2 + (size_t)l * kD * 1536;
        const float* f2b = fc2b + l * kD;

        // qkv GEMM, LN folded into weights (coef from qcoef) -> split BF16 q/k/v
        k_mgemm<0, 1, 1, 0><<<8 * 18 * 25, 256, 0, stream>>>(
            (const void*)cur, kD, (const unsigned short*)qw, kD,
            qb, (unsigned short*)qsplit, 1152, (const void*)nullptr, (const int*)nullptr,
            (const float2*)(qcoef + (size_t)l * 1152),
            197, 18, kBAND, si, 0,
            (const float2*)pstats, (float2*)nullptr);
        // decision: coalesced producers (transposed imph) + 1-block finalize
        k_decA<<<kB * kH, 256, 0, stream>>>(qsplit, imph, sabh, si);
        k_decB<<<1, 256, 0, stream>>>(si, sf, imph, sabh, keep);
        // attention on pruned tokens
        k_attn2<<<kB * kH, 256, 0, stream>>>(qsplit, obuf, si, keep);
        // proj + pruned bf16 residual (gather via keep), write other buffer, emit stats
        k_mgemm<0, 0, 0, 1><<<8 * 6 * 25, 256, 0, stream>>>(
            (const void*)obuf, kD, (const unsigned short*)pw, kD,
            pb, oth, kD, (const void*)cur, keep,
            (const float2*)nullptr,
            197, 6, kBAND, si, 0,
            (const float2*)nullptr, pstats);
        { unsigned short* tmp = cur; cur = oth; oth = tmp; }
        // fc1, LN folded into weights (coef from fcoef) -> bf16 hbuf, gelu
        k_mgemm<1, 0, 1, 0><<<8 * 24 * 25, 256, 0, stream>>>(
            (const void*)cur, kD, (const unsigned short*)f1w, kD,
            f1b, (unsigned short*)hbuf, 1536, (const void*)nullptr, (const int*)nullptr,
            (const float2*)(fcoef + (size_t)l * 1536),
            197, 24, kBAND, si, 0,
            (const float2*)pstats, (float2*)nullptr);
        // fc2 + bf16 residual (in place on cur), emit stats for next layer
        k_mgemm<0, 0, 0, 1><<<8 * 6 * 25, 256, 0, stream>>>(
            (const void*)hbuf, 1536, (const unsigned short*)f2w, 1536,
            f2b, cur, kD, (const void*)cur, (const int*)nullptr,
            (const float2*)nullptr,
            197, 6, kBAND, si, 0,
            (const float2*)nullptr, pstats);
    }

    k_head<<<kB * 4, 256, 0, stream>>>(cur, normw, normb, headw, headb, out);
}

// Round 16
// 1096.423 us; speedup vs baseline: 1.0877x; 1.0554x over previous
//
#include <hip/hip_runtime.h>
#include <hip/hip_bf16.h>

// ---------------- constants ----------------
static constexpr int kL = 12;
static constexpr int kD = 384;
static constexpr int kH = 6;
static constexpr int kB = 64;
static constexpr int kNP = 196;      // patches
static constexpr int kBAND = 197;    // tokens incl cls (max)
static constexpr int kNCLS = 1000;
static constexpr float kSCALE = 0.125f;   // 64^-0.5
static constexpr float kEPS = 1e-6f;
static constexpr size_t kWQ = (size_t)kB * kH * kBAND * 64;   // per-tensor elems in split qkv
static constexpr int kBH = kB * kH;                            // 384

typedef __attribute__((ext_vector_type(8))) short short8;
typedef __attribute__((ext_vector_type(4))) float f32x4;

__device__ __forceinline__ float gelu_f(float x) {
    return 0.5f * x * (1.0f + erff(x * 0.70710678118654752440f));
}
__device__ __forceinline__ unsigned short f2bf(float x) {
    __hip_bfloat16 h = __float2bfloat16(x);
    return *(unsigned short*)&h;
}
__device__ __forceinline__ float bf2f(unsigned short u) {
    unsigned int x = ((unsigned int)u) << 16;
    return __uint_as_float(x);
}

// ---------------- init: state + cls rows of xtA (bf16) + cls-row LN partials ----------------
__global__ __launch_bounds__(384) void k_init(int* si, float* sf,
                                              const float* __restrict__ cls,
                                              const float* __restrict__ pos,
                                              unsigned short* __restrict__ xtA,
                                              float2* __restrict__ pstats) {
    int b = blockIdx.x, c = threadIdx.x;
    unsigned short hv = f2bf(cls[c] + pos[c]);
    xtA[(size_t)b * kBAND * kD + c] = hv;
    float v = bf2f(hv);                      // stats of the ROUNDED value
    __shared__ float r1[384], r2[384];
    r1[c] = v; r2[c] = v * v;
    __syncthreads();
    if (c < 128) { r1[c] += r1[c + 128] + r1[c + 256]; r2[c] += r2[c + 128] + r2[c + 256]; }
    __syncthreads();
    for (int st = 64; st; st >>= 1) {
        if (c < st) { r1[c] += r1[c + st]; r2[c] += r2[c + st]; }
        __syncthreads();
    }
    if (c == 0) {
        pstats[(size_t)(b * kBAND) * 8 + 0] = make_float2(r1[0], r2[0]);
#pragma unroll
        for (int nn = 1; nn < 6; ++nn) pstats[(size_t)(b * kBAND) * 8 + nn] = make_float2(0.f, 0.f);
        if (b == 0) { si[0] = kBAND; sf[0] = 1.0f; }
    }
}

// ---------------- fp32 -> bf16 weight conversion; fold LN gamma into qkvw/fc1w ------------
__global__ __launch_bounds__(256) void k_cvtall(
    const float* __restrict__ s0, const float* __restrict__ s1, const float* __restrict__ s2,
    const float* __restrict__ s3, const float* __restrict__ s4,
    const float* __restrict__ lw1, const float* __restrict__ lw2,
    __hip_bfloat16* __restrict__ d0, __hip_bfloat16* __restrict__ d1, __hip_bfloat16* __restrict__ d2,
    __hip_bfloat16* __restrict__ d3, __hip_bfloat16* __restrict__ d4) {
    const int c0 = 73728, c1 = 1400832, c2 = 1843200, c3 = 3612672, c4 = 5382144;
    int stride = gridDim.x * 256;
    for (int i = blockIdx.x * 256 + threadIdx.x; i < c4; i += stride) {
        const float* src; __hip_bfloat16* dst; int off; int fold = 0;
        const float* lw = nullptr; int perL = 0;
        if (i < c0)      { src = s0; dst = d0; off = i; }
        else if (i < c1) { src = s1; dst = d1; off = i - c0; fold = 1; lw = lw1; perL = 442368; }
        else if (i < c2) { src = s2; dst = d2; off = i - c1; }
        else if (i < c3) { src = s3; dst = d3; off = i - c2; fold = 1; lw = lw2; perL = 589824; }
        else             { src = s4; dst = d4; off = i - c3; }
        float4 v = ((const float4*)src)[off];
        if (fold) {
            int f0 = off << 2;
            int l = f0 / perL;
            int k = f0 % 384;
            float4 g = *(const float4*)(lw + l * 384 + k);
            v.x *= g.x; v.y *= g.y; v.z *= g.z; v.w *= g.w;
        }
        dst[4 * off + 0] = __float2bfloat16(v.x);
        dst[4 * off + 1] = __float2bfloat16(v.y);
        dst[4 * off + 2] = __float2bfloat16(v.z);
        dst[4 * off + 3] = __float2bfloat16(v.w);
    }
}

// ---------------- LN-fold per-column coefficients: G = sum(bf16(gW)), Bn = sum(lnb*W) ------
__global__ __launch_bounds__(256) void k_lncoef(
    const unsigned short* __restrict__ wq, const float* __restrict__ qkvw_f, const float* __restrict__ ln1b,
    const unsigned short* __restrict__ wf, const float* __restrict__ fc1w_f, const float* __restrict__ ln2b,
    float2* __restrict__ qcoef, float2* __restrict__ fcoef) {
    const int NQ = kL * 1152;
    const int NF = kL * 1536;
    int col = blockIdx.x * 4 + (threadIdx.x >> 6);
    int lane = threadIdx.x & 63;
    if (col >= NQ + NF) return;
    bool isQ = col < NQ;
    int c = isQ ? col : col - NQ;
    int l = c / (isQ ? 1152 : 1536);
    const unsigned short* w = (isQ ? wq : wf) + (size_t)c * 384;
    const float* wo = (isQ ? qkvw_f : fc1w_f) + (size_t)c * 384;
    const float* lb = (isQ ? ln1b : ln2b) + l * 384;
    float g = 0.f, bn = 0.f;
#pragma unroll
    for (int e = 0; e < 6; ++e) {
        int k = lane + (e << 6);
        g += bf2f(w[k]);
        bn += lb[k] * wo[k];
    }
#pragma unroll
    for (int off = 1; off < 64; off <<= 1) { g += __shfl_xor(g, off, 64); bn += __shfl_xor(bn, off, 64); }
    if (lane == 0) { if (isQ) qcoef[c] = make_float2(g, bn); else fcoef[c] = make_float2(g, bn); }
}

// ---------------- bf16 MFMA GEMM: 64x64 tile, ping-pong LDS double-buffer ----------------
// XCD-pinned 1-D grid: L -> (xcd=L&7, n=(L>>3)%nT, r=((L>>3)/nT)*8+xcd).
// Virtual row compaction: rv in [0,64*Nt) -> (b=rv/Nt, t=rv%Nt), phys row b*band+t.
// Residual stream is BF16 everywhere.
// LNA==1: LN folded into weights; epilogue v = rs*acc + bias + Bn - mu*rs*G.
// STATS==1: store pass emits per-(row, 64-col-slice) (sum,sumsq) of ROUNDED stores.
// MODE: 0 normal (R bf16 residual, keepR gather), 1 qkv head-split store,
//       2 patch: A on-the-fly from fp32 image (im2col fused), +patch_b, +pos(fp32), row t+1.
// K-loop: single barrier per step; loads for step k+1 issued before MFMA of step k.
template<int ACT_GELU, int MODE, int LNA, int STATS>
__global__ __launch_bounds__(256) void k_mgemm(
    const void* __restrict__ Av, int lda,
    const unsigned short* __restrict__ W, int K,
    const float* __restrict__ bias,
    unsigned short* __restrict__ Cv, int ldc,
    const void* __restrict__ Rv,
    const int* __restrict__ keepR,
    const float2* __restrict__ lncoef,
    int rT, int nT, int band,
    const int* __restrict__ NtPtr, int ntConst,
    const float2* __restrict__ pstatsIn, float2* __restrict__ pstatsOut)
{
    __shared__ __align__(16) unsigned char pool[36864];
    typedef unsigned short lds_t[64][72];
    lds_t* As = (lds_t*)pool;                      // As[0], As[1]: 2 x 9216B
    lds_t* Ws = (lds_t*)(pool + 18432);            // Ws[0], Ws[1]: 2 x 9216B
    unsigned short (*Cu)[76] = (unsigned short (*)[76])pool;   // 64x76 u16 overlay
    __shared__ float mus[64], rss[64];

    int Nt = NtPtr ? NtPtr[0] : ntConst;
    unsigned int rowsTotal = (unsigned int)kB * (unsigned int)Nt;

    int L = blockIdx.x;
    int xcd = L & 7;
    int m = L >> 3;
    int n = m % nT;
    int r = (m / nT) * 8 + xcd;
    if (r >= rT) return;
    unsigned int r0 = (unsigned int)r * 64;
    int n0 = n * 64;
    if (r0 >= rowsTotal) return;

    const float* Rf = (const float*)Rv;                    // MODE 2: pos (fp32)
    const unsigned short* Rb = (const unsigned short*)Rv;  // MODE 0: residual (bf16)

    int tid = threadIdx.x;
    int srow = tid >> 3;            // 0..31
    int scol = (tid & 7) << 3;      // 0..56 step 8

    unsigned int rv0 = r0 + srow, rv1 = r0 + srow + 32;
    bool v0 = rv0 < rowsTotal, v1 = rv1 < rowsTotal;
    const unsigned short* ah0 = nullptr; const unsigned short* ah1 = nullptr;
    const float* xb0 = nullptr; const float* xb1 = nullptr;   // MODE 2 image bases
    if (MODE == 2) {
        if (v0) {
            unsigned int bb = rv0 / (unsigned int)Nt, tt = rv0 - bb * Nt;
            int py = tt / 14, px = tt - py * 14;
            xb0 = (const float*)Av + (size_t)bb * 3 * 224 * 224 + (py * 16) * 224 + px * 16;
        }
        if (v1) {
            unsigned int bb = rv1 / (unsigned int)Nt, tt = rv1 - bb * Nt;
            int py = tt / 14, px = tt - py * 14;
            xb1 = (const float*)Av + (size_t)bb * 3 * 224 * 224 + (py * 16) * 224 + px * 16;
        }
    } else {
        if (v0) {
            unsigned int bb = rv0 / (unsigned int)Nt, tt = rv0 - bb * Nt;
            ah0 = (const unsigned short*)Av + ((size_t)bb * band + tt) * lda;
        }
        if (v1) {
            unsigned int bb = rv1 / (unsigned int)Nt, tt = rv1 - bb * Nt;
            ah1 = (const unsigned short*)Av + ((size_t)bb * band + tt) * lda;
        }
    }
    const unsigned short* wp0 = W + (size_t)(n0 + srow) * K;
    const unsigned short* wp1 = W + (size_t)(n0 + srow + 32) * K;

    if (LNA) {
        if (tid < 64) {
            unsigned int rv = r0 + tid;
            float mu = 0.f, rsd = 0.f;
            if (rv < rowsTotal) {
                unsigned int bb = rv / (unsigned int)Nt, tt = rv - bb * Nt;
                const float2* ps = pstatsIn + ((size_t)bb * band + tt) * 8;
                float s1 = 0.f, s2 = 0.f;
#pragma unroll
                for (int nn = 0; nn < 6; ++nn) { float2 p = ps[nn]; s1 += p.x; s2 += p.y; }
                mu = s1 * (1.f / 384.f);
                float var = fmaxf(s2 * (1.f / 384.f) - mu * mu, 0.f);
                rsd = rsqrtf(var + kEPS);
            }
            mus[tid] = mu; rss[tid] = rsd;
        }
        // visibility ensured by the staging barrier before first MFMA
    }

    auto loadAB = [&](int k0, uint4& a0, uint4& a1, uint4& w0, uint4& w1) {
        uint4 zero = make_uint4(0, 0, 0, 0);
        a0 = zero; a1 = zero;
        w0 = *(const uint4*)(wp0 + k0 + scol);
        w1 = *(const uint4*)(wp1 + k0 + scol);
        if (MODE == 2) {
            int k = k0 + scol;
            int c = k >> 8;
            int rr_ = k & 255;
            int ky = rr_ >> 4, kx = rr_ & 15;
            size_t off = (size_t)c * 50176 + (size_t)ky * 224 + kx;
            if (v0) {
                float4 x0 = *(const float4*)(xb0 + off);
                float4 x1 = *(const float4*)(xb0 + off + 4);
                unsigned short p[8];
                p[0] = f2bf(x0.x); p[1] = f2bf(x0.y); p[2] = f2bf(x0.z); p[3] = f2bf(x0.w);
                p[4] = f2bf(x1.x); p[5] = f2bf(x1.y); p[6] = f2bf(x1.z); p[7] = f2bf(x1.w);
                a0 = *(uint4*)p;
            }
            if (v1) {
                float4 x0 = *(const float4*)(xb1 + off);
                float4 x1 = *(const float4*)(xb1 + off + 4);
                unsigned short p[8];
                p[0] = f2bf(x0.x); p[1] = f2bf(x0.y); p[2] = f2bf(x0.z); p[3] = f2bf(x0.w);
                p[4] = f2bf(x1.x); p[5] = f2bf(x1.y); p[6] = f2bf(x1.z); p[7] = f2bf(x1.w);
                a1 = *(uint4*)p;
            }
        } else {
            if (v0) a0 = *(const uint4*)(ah0 + k0 + scol);
            if (v1) a1 = *(const uint4*)(ah1 + k0 + scol);
        }
    };

    int wave = tid >> 6, lane = tid & 63;
    int wr32 = ((wave >> 1) & 1) * 32, wc32 = (wave & 1) * 32;
    int l15 = lane & 15, l4 = lane >> 4;

    f32x4 acc00 = {}, acc01 = {}, acc10 = {}, acc11 = {};

    // prologue: stage k0=0 into buffer 0
    uint4 a0, a1, w0, w1;
    loadAB(0, a0, a1, w0, w1);
    *(uint4*)&As[0][srow][scol] = a0;
    *(uint4*)&As[0][srow + 32][scol] = a1;
    *(uint4*)&Ws[0][srow][scol] = w0;
    *(uint4*)&Ws[0][srow + 32][scol] = w1;
    __syncthreads();

    int cur = 0;
    for (int k0 = 0; ;) {
        int kn = k0 + 64;
        bool more = kn < K;
        if (more) loadAB(kn, a0, a1, w0, w1);   // loads in flight during MFMA
#pragma unroll
        for (int ks = 0; ks < 2; ++ks) {
            short8 af_0 = *(const short8*)&As[cur][wr32 + l15][ks * 32 + l4 * 8];
            short8 af_1 = *(const short8*)&As[cur][wr32 + 16 + l15][ks * 32 + l4 * 8];
            short8 bf_0 = *(const short8*)&Ws[cur][wc32 + l15][ks * 32 + l4 * 8];
            short8 bf_1 = *(const short8*)&Ws[cur][wc32 + 16 + l15][ks * 32 + l4 * 8];
            acc00 = __builtin_amdgcn_mfma_f32_16x16x32_bf16(af_0, bf_0, acc00, 0, 0, 0);
            acc01 = __builtin_amdgcn_mfma_f32_16x16x32_bf16(af_0, bf_1, acc01, 0, 0, 0);
            acc10 = __builtin_amdgcn_mfma_f32_16x16x32_bf16(af_1, bf_0, acc10, 0, 0, 0);
            acc11 = __builtin_amdgcn_mfma_f32_16x16x32_bf16(af_1, bf_1, acc11, 0, 0, 0);
        }
        if (!more) break;
        int nxt = cur ^ 1;
        *(uint4*)&As[nxt][srow][scol] = a0;
        *(uint4*)&As[nxt][srow + 32][scol] = a1;
        *(uint4*)&Ws[nxt][srow][scol] = w0;
        *(uint4*)&Ws[nxt][srow + 32][scol] = w1;
        __syncthreads();           // one barrier per K-step
        cur = nxt; k0 = kn;
    }

    // -------- epilogue: LN-fold / bias / act / residual, stage bf16 tile in LDS --------
    __syncthreads();
    f32x4 accs[2][2] = { { acc00, acc01 }, { acc10, acc11 } };
#pragma unroll
    for (int fi = 0; fi < 2; ++fi) {
        int lrow = wr32 + fi * 16 + l4 * 4;
        unsigned int rvb = r0 + lrow;
#pragma unroll
        for (int fj = 0; fj < 2; ++fj) {
            int lcol = wc32 + fj * 16 + l15;
            float bv = bias ? bias[n0 + lcol] : 0.f;
            float2 cf = make_float2(0.f, 0.f);
            if (LNA) cf = lncoef[n0 + lcol];
#pragma unroll
            for (int rr = 0; rr < 4; ++rr) {
                unsigned int rv = rvb + rr;
                float v;
                if (LNA) {
                    float muv = mus[lrow + rr], rsv = rss[lrow + rr];
                    v = accs[fi][fj][rr] * rsv + bv + cf.y - muv * rsv * cf.x;
                } else {
                    v = accs[fi][fj][rr] + bv;
                }
                if (ACT_GELU) v = gelu_f(v);
                if (MODE == 2) {
                    if (rv < rowsTotal) {
                        unsigned int bb = rv / (unsigned int)Nt;
                        unsigned int tt = rv - bb * (unsigned int)Nt;
                        v += Rf[(size_t)(tt + 1) * kD + n0 + lcol];
                    }
                } else if (Rv && rv < rowsTotal) {
                    unsigned int bb = rv / (unsigned int)Nt;
                    unsigned int tt = rv - bb * (unsigned int)Nt;
                    size_t rrow = keepR ? ((size_t)bb * band + keepR[tt]) : ((size_t)bb * band + tt);
                    v += bf2f(Rb[rrow * ldc + n0 + lcol]);
                }
                Cu[lrow + rr][lcol] = f2bf(v);
            }
        }
    }
    __syncthreads();

    // -------- coalesced stores (+ optional LN partial-stats emit) --------
#pragma unroll
    for (int i = 0; i < 2; ++i) {
        int id = tid + (i << 8);
        int row = id >> 3, c2 = id & 7;
        unsigned int rv = r0 + row;
        if (rv < rowsTotal) {
            unsigned int bb = rv / (unsigned int)Nt;
            unsigned int tt = rv - bb * (unsigned int)Nt;
            uint4 val = *(const uint4*)&Cu[row][c2 << 3];
            if (MODE == 1) {
                int which = n0 >= 768 ? 2 : (n0 >= 384 ? 1 : 0);
                int hh = (n0 - which * 384) >> 6;
                *(uint4*)(Cv + (size_t)which * kWQ +
                          (((size_t)bb * kH + hh) * kBAND + tt) * 64 + ((n0 & 63) + (c2 << 3))) = val;
            } else if (MODE == 2) {
                *(uint4*)(Cv + ((size_t)bb * kBAND + tt + 1) * ldc + n0 + (c2 << 3)) = val;
            } else {
                *(uint4*)(Cv + ((size_t)bb * band + tt) * ldc + n0 + (c2 << 3)) = val;
            }
            if (STATS) {
                const unsigned short* u = (const unsigned short*)&val;
                float s1 = 0.f, s2 = 0.f;
#pragma unroll
                for (int e = 0; e < 8; ++e) { float f = bf2f(u[e]); s1 += f; s2 += f * f; }
#pragma unroll
                for (int off = 1; off < 8; off <<= 1) {
                    s1 += __shfl_xor(s1, off, 64);
                    s2 += __shfl_xor(s2, off, 64);
                }
                if (c2 == 0) {
                    size_t sridx = (MODE == 2) ? ((size_t)bb * kBAND + tt + 1)
                                               : ((size_t)bb * band + tt);
                    pstatsOut[sridx * 8 + n] = make_float2(s1, s2);
                }
            }
        }
    }
}

// ---------------- decision A: per-(b,h) importance; imph stored TRANSPOSED [token][bh] ------
__global__ __launch_bounds__(256) void k_decA(const __hip_bfloat16* __restrict__ qsplit,
                                              float* __restrict__ imph, float* __restrict__ sabh,
                                              const int* __restrict__ si) {
    int Nt = si[0];
    if (Nt - 1 <= 16) return;
    int tid = threadIdx.x, w = tid >> 6, lane = tid & 63;
    int bh = blockIdx.x;
    __shared__ float qs[64];
    __shared__ float sdot[224], svn[224];
    __shared__ float red[256];
    const __hip_bfloat16* qp = qsplit + (size_t)bh * kBAND * 64;
    const __hip_bfloat16* kp = qsplit + kWQ + (size_t)bh * kBAND * 64;
    const __hip_bfloat16* vp = qsplit + 2 * kWQ + (size_t)bh * kBAND * 64;
    if (tid < 64) qs[tid] = __bfloat162float(qp[tid]);   // cls q
    __syncthreads();
    float qv = qs[lane];
    for (int j = w; j < Nt; j += 8) {
        int j2 = j + 4;
        bool has2 = j2 < Nt;
        float k1 = __bfloat162float(kp[(size_t)j * 64 + lane]);
        float v1 = __bfloat162float(vp[(size_t)j * 64 + lane]);
        float k2 = has2 ? __bfloat162float(kp[(size_t)j2 * 64 + lane]) : 0.f;
        float v2 = has2 ? __bfloat162float(vp[(size_t)j2 * 64 + lane]) : 0.f;
        float p1 = qv * k1, n1 = v1 * v1;
        float p2 = qv * k2, n2 = v2 * v2;
#pragma unroll
        for (int off = 1; off < 64; off <<= 1) {
            p1 += __shfl_xor(p1, off, 64); n1 += __shfl_xor(n1, off, 64);
            p2 += __shfl_xor(p2, off, 64); n2 += __shfl_xor(n2, off, 64);
        }
        if (lane == 0) {
            sdot[j] = p1 * kSCALE; svn[j] = sqrtf(n1);
            if (has2) { sdot[j2] = p2 * kSCALE; svn[j2] = sqrtf(n2); }
        }
    }
    __syncthreads();
    float s = (tid < Nt) ? sdot[tid] : -INFINITY;
    red[tid] = s; __syncthreads();
    for (int st = 128; st; st >>= 1) { if (tid < st) red[tid] = fmaxf(red[tid], red[tid + st]); __syncthreads(); }
    float mmax = red[0]; __syncthreads();
    float e = (tid < Nt) ? expf(s - mmax) : 0.f;
    red[tid] = e; __syncthreads();
    for (int st = 128; st; st >>= 1) { if (tid < st) red[tid] += red[tid + st]; __syncthreads(); }
    float inv = 1.f / red[0];
    float val = (tid < Nt) ? e * inv * svn[tid] : 0.f;
    if (tid < Nt) imph[(size_t)tid * kBH + bh] = val;    // transposed
    __syncthreads();
    red[tid] = val; __syncthreads();
    for (int st = 128; st; st >>= 1) { if (tid < st) red[tid] += red[tid + st]; __syncthreads(); }
    if (tid == 0) { sabh[2 * bh] = red[0]; sabh[2 * bh + 1] = val; }   // tid0 val = token 0
}

// ---------------- decision B: finalize (1 block): mass/ratio, top-k, keep, commit Nt --------
__global__ __launch_bounds__(256) void k_decB(int* __restrict__ si, float* __restrict__ sf,
                                              const float* __restrict__ imph,
                                              const float* __restrict__ sabh,
                                              int* __restrict__ keep) {
    int Nt = si[0];
    int tid = threadIdx.x;
    if (Nt - 1 <= 16) {
        for (int j = tid; j < Nt; j += 256) keep[j] = j;
        return;
    }
    int N = Nt - 1;
    __shared__ float red[256];
    float v = 0.f;
    if (tid < kB) {
        float sa = 0.f, i0 = 0.f;
#pragma unroll
        for (int hh = 0; hh < kH; ++hh) {
            sa += sabh[2 * (tid * kH + hh)];
            i0 += sabh[2 * (tid * kH + hh) + 1];
        }
        sa *= (1.f / 6.f); i0 *= (1.f / 6.f);
        v = (sa - i0) / (sa + kEPS);
    }
    red[tid] = v; __syncthreads();
    for (int st = 128; st; st >>= 1) { if (tid < st) red[tid] += red[tid + st]; __syncthreads(); }
    float mass = red[0] * (1.f / 64.f);
    float prev = sf[0];
    float ratio = 0.5f * mass / (prev + kEPS);
    ratio = fminf(fmaxf(ratio, 0.f), 1.f);
    int N_next = (int)((double)N * (double)ratio);
    if (N_next < 16) N_next = 16;
    if (tid == 0) sf[0] = mass;
    __syncthreads();
    if (N_next >= N) {
        for (int j = tid; j < Nt; j += 256) keep[j] = j;
        return;
    }
    __shared__ float scq[200][4];
    __shared__ float sc[200];
    __shared__ int flag[200];
    for (int task = tid; task < N * 4; task += 256) {
        int row = task >> 2, seg = task & 3;
        const float4* p = (const float4*)(imph + (size_t)(row + 1) * kBH) + seg * 24;
        float a0 = 0.f, a1 = 0.f, a2 = 0.f, a3 = 0.f;
#pragma unroll
        for (int q = 0; q < 24; q += 4) {
            float4 x0 = p[q + 0], x1 = p[q + 1], x2 = p[q + 2], x3 = p[q + 3];
            a0 += (x0.x + x0.y) + (x0.z + x0.w);
            a1 += (x1.x + x1.y) + (x1.z + x1.w);
            a2 += (x2.x + x2.y) + (x2.z + x2.w);
            a3 += (x3.x + x3.y) + (x3.z + x3.w);
        }
        scq[row][seg] = (a0 + a1) + (a2 + a3);
    }
    __syncthreads();
    if (tid < N) sc[tid] = (scq[tid][0] + scq[tid][1]) + (scq[tid][2] + scq[tid][3]);
    __syncthreads();
    if (tid < N) {
        float s2 = sc[tid];
        int rank = 0;
        for (int i = 0; i < N; ++i) {
            float o2 = sc[i];
            rank += (o2 > s2) || (o2 == s2 && i < tid);
        }
        flag[tid] = (rank < N_next) ? 1 : 0;
    }
    __syncthreads();
    if (tid == 0) {
        keep[0] = 0;
        int pos = 1;
        for (int j = 0; j < N; ++j) if (flag[j]) keep[pos++] = j + 1;
        si[0] = N_next + 1;
    }
}

// ---------------- MFMA flash attention: one block per (b,h) (bf16 qsplit) ----------------
__global__ __launch_bounds__(256) void k_attn2(const __hip_bfloat16* __restrict__ qsplit,
                                               __hip_bfloat16* __restrict__ o,
                                               const int* __restrict__ si,
                                               const int* __restrict__ keep) {
    __shared__ __align__(16) unsigned short Kb[224][72];
    __shared__ __align__(16) unsigned short Vt[64][228];
    __shared__ __align__(16) unsigned short Pb[4][16][228];
    int Nt = si[0];
    int bh = blockIdx.x;
    int b = bh / kH, h = bh - b * kH;
    int tid = threadIdx.x, w = tid >> 6, lane = tid & 63;
    int l15 = lane & 15, l4 = lane >> 4;
    int nJT = (Nt + 15) >> 4;
    int nKT = (Nt + 31) >> 5;
    int NTP = nKT << 5;

    const unsigned short* qb = (const unsigned short*)qsplit + (size_t)bh * kBAND * 64;
    const unsigned short* kb = (const unsigned short*)qsplit + kWQ + (size_t)bh * kBAND * 64;
    const unsigned short* vb = (const unsigned short*)qsplit + 2 * kWQ + (size_t)bh * kBAND * 64;

    {
        int rr = tid >> 3;
        int c8 = (tid & 7) << 3;
        for (int r = rr; r < NTP; r += 32) {
            uint4 kv = make_uint4(0, 0, 0, 0), vv = make_uint4(0, 0, 0, 0);
            if (r < Nt) {
                int old = keep[r];
                kv = *(const uint4*)(kb + ((size_t)old << 6) + c8);
                vv = *(const uint4*)(vb + ((size_t)old << 6) + c8);
            }
            *(uint4*)&Kb[r][c8] = kv;
            const unsigned short* vs = (const unsigned short*)&vv;
#pragma unroll
            for (int e = 0; e < 8; ++e) Vt[c8 + e][r] = vs[e];
        }
    }
    __syncthreads();

    for (int strip = w; strip < nJT; strip += 4) {
        int tq = (strip << 4) + l15;
        int told = (tq < Nt) ? keep[tq] : 0;
        const unsigned short* qrow = qb + ((size_t)told << 6) + (l4 << 3);
        short8 qf0 = *(const short8*)(qrow);
        short8 qf1 = *(const short8*)(qrow + 32);

        f32x4 sv[13];
#pragma unroll
        for (int jt = 0; jt < 13; ++jt) {
            if (jt < nJT) {
                const unsigned short* kr = &Kb[(jt << 4) + l15][l4 << 3];
                short8 kf0 = *(const short8*)(kr);
                short8 kf1 = *(const short8*)(kr + 32);
                f32x4 a = {};
                a = __builtin_amdgcn_mfma_f32_16x16x32_bf16(qf0, kf0, a, 0, 0, 0);
                a = __builtin_amdgcn_mfma_f32_16x16x32_bf16(qf1, kf1, a, 0, 0, 0);
                sv[jt] = a;
            }
        }
        float mx[4] = { -INFINITY, -INFINITY, -INFINITY, -INFINITY };
#pragma unroll
        for (int jt = 0; jt < 13; ++jt) if (jt < nJT) {
            bool ok = ((jt << 4) + l15) < Nt;
#pragma unroll
            for (int r = 0; r < 4; ++r) {
                float s = ok ? sv[jt][r] * kSCALE : -INFINITY;
                sv[jt][r] = s;
                mx[r] = fmaxf(mx[r], s);
            }
        }
#pragma unroll
        for (int r = 0; r < 4; ++r) {
            mx[r] = fmaxf(mx[r], __shfl_xor(mx[r], 1, 64));
            mx[r] = fmaxf(mx[r], __shfl_xor(mx[r], 2, 64));
            mx[r] = fmaxf(mx[r], __shfl_xor(mx[r], 4, 64));
            mx[r] = fmaxf(mx[r], __shfl_xor(mx[r], 8, 64));
        }
        float sm[4] = { 0.f, 0.f, 0.f, 0.f };
#pragma unroll
        for (int jt = 0; jt < 13; ++jt) if (jt < nJT) {
#pragma unroll
            for (int r = 0; r < 4; ++r) {
                float p = expf(sv[jt][r] - mx[r]);
                sv[jt][r] = p;
                sm[r] += p;
            }
        }
#pragma unroll
        for (int r = 0; r < 4; ++r) {
            sm[r] += __shfl_xor(sm[r], 1, 64);
            sm[r] += __shfl_xor(sm[r], 2, 64);
            sm[r] += __shfl_xor(sm[r], 4, 64);
            sm[r] += __shfl_xor(sm[r], 8, 64);
            sm[r] = 1.f / sm[r];
        }
#pragma unroll
        for (int jt = 0; jt < 13; ++jt) if (jt < nJT) {
#pragma unroll
            for (int r = 0; r < 4; ++r)
                Pb[w][(l4 << 2) + r][(jt << 4) + l15] = f2bf(sv[jt][r] * sm[r]);
        }
        for (int c = (nJT << 4) + lane; c < NTP; c += 64) {
#pragma unroll
            for (int rr2 = 0; rr2 < 16; ++rr2) Pb[w][rr2][c] = 0;
        }
        asm volatile("s_waitcnt lgkmcnt(0)" ::: "memory");
        __builtin_amdgcn_sched_barrier(0);

        f32x4 oacc[4] = { {}, {}, {}, {} };
#pragma unroll
        for (int kt = 0; kt < 7; ++kt) if (kt < nKT) {
            short8 pf = *(const short8*)&Pb[w][l15][(kt << 5) + (l4 << 3)];
#pragma unroll
            for (int dt = 0; dt < 4; ++dt) {
                short8 vf = *(const short8*)&Vt[(dt << 4) + l15][(kt << 5) + (l4 << 3)];
                oacc[dt] = __builtin_amdgcn_mfma_f32_16x16x32_bf16(pf, vf, oacc[dt], 0, 0, 0);
            }
        }
#pragma unroll
        for (int dt = 0; dt < 4; ++dt) {
#pragma unroll
            for (int r = 0; r < 4; ++r) {
                int tqo = (strip << 4) + (l4 << 2) + r;
                if (tqo < Nt)
                    o[((size_t)b * kBAND + tqo) * kD + h * 64 + (dt << 4) + l15] =
                        __float2bfloat16(oacc[dt][r]);
            }
        }
    }
}

// ---------------- head with fused final LayerNorm (bf16 residual in) ----------------
__global__ __launch_bounds__(256) void k_head(const unsigned short* __restrict__ X,
                                              const float* __restrict__ nw, const float* __restrict__ nb,
                                              const float* __restrict__ hw, const float* __restrict__ hb,
                                              float* __restrict__ out) {
    int b = blockIdx.x >> 2;
    int tid = threadIdx.x;
    __shared__ float xs[384];
    __shared__ float red[256];
    const unsigned short* row = X + (size_t)b * kBAND * kD;
    float s1 = 0.f, s2 = 0.f;
    for (int c = tid; c < 384; c += 256) { float v = bf2f(row[c]); xs[c] = v; s1 += v; s2 += v * v; }
    red[tid] = s1; __syncthreads();
    for (int st = 128; st; st >>= 1) { if (tid < st) red[tid] += red[tid + st]; __syncthreads(); }
    float sum = red[0]; __syncthreads();
    red[tid] = s2; __syncthreads();
    for (int st = 128; st; st >>= 1) { if (tid < st) red[tid] += red[tid + st]; __syncthreads(); }
    float sq = red[0];
    float mu = sum * (1.f / 384.f);
    float var = fmaxf(sq * (1.f / 384.f) - mu * mu, 0.f);
    float rs = rsqrtf(var + kEPS);
    __syncthreads();
    for (int c = tid; c < 384; c += 256) xs[c] = (xs[c] - mu) * rs * nw[c] + nb[c];
    __syncthreads();
    int n = ((blockIdx.x & 3) << 8) + tid;
    if (n >= kNCLS) return;
    const float* wrow = hw + (size_t)n * kD;
    float acc = 0.f;
#pragma unroll 8
    for (int d = 0; d < kD; d += 4) {
        float4 w4 = *(const float4*)(wrow + d);
        acc += xs[d] * w4.x + xs[d + 1] * w4.y + xs[d + 2] * w4.z + xs[d + 3] * w4.w;
    }
    out[(size_t)b * kNCLS + n] = acc + hb[n];
}

// ---------------- host launch ----------------
extern "C" void kernel_launch(void* const* d_in, const int* in_sizes, int n_in,
                              void* d_out, int out_size, void* d_ws, size_t ws_size,
                              hipStream_t stream) {
    const float* x       = (const float*)d_in[0];
    const float* patch_w = (const float*)d_in[1];
    const float* patch_b = (const float*)d_in[2];
    const float* cls_tok = (const float*)d_in[3];
    const float* pos     = (const float*)d_in[4];
    const float* ln1w    = (const float*)d_in[5];
    const float* ln1b    = (const float*)d_in[6];
    const float* qkvw    = (const float*)d_in[7];
    const float* qkvb    = (const float*)d_in[8];
    const float* projw   = (const float*)d_in[9];
    const float* projb   = (const float*)d_in[10];
    const float* ln2w    = (const float*)d_in[11];
    const float* ln2b    = (const float*)d_in[12];
    const float* fc1w    = (const float*)d_in[13];
    const float* fc1b    = (const float*)d_in[14];
    const float* fc2w    = (const float*)d_in[15];
    const float* fc2b    = (const float*)d_in[16];
    const float* normw   = (const float*)d_in[17];
    const float* normb   = (const float*)d_in[18];
    const float* headw   = (const float*)d_in[19];
    const float* headb   = (const float*)d_in[20];
    float* out = (float*)d_out;

    char* ws = (char*)d_ws;
    const size_t MB = 1024ull * 1024ull;
    int*   si   = (int*)ws;                    // si[0]=Nt
    float* sf   = (float*)(ws + 64);
    int*   keep = (int*)(ws + 256);
    float* sabh = (float*)(ws + 4096);         // 384*2 f32
    float* imph = (float*)(ws + 16384);        // 197*384 f32 transposed ~ 303 KB
    unsigned short* xtA = (unsigned short*)(ws + 1 * MB);     // 9.7 MB bf16 residual
    unsigned short* xtB = (unsigned short*)(ws + 12 * MB);    // 9.7 MB bf16 residual
    __hip_bfloat16* obuf = (__hip_bfloat16*)(ws + 23 * MB);   // 9.7 MB attn out
    __hip_bfloat16* qsplit = (__hip_bfloat16*)(ws + 33 * MB); // 29 MB bf16
    __hip_bfloat16* hbuf   = (__hip_bfloat16*)(ws + 33 * MB); // fc1 out (aliases qsplit)
    __hip_bfloat16* wpat = (__hip_bfloat16*)(ws + 110 * MB);
    __hip_bfloat16* wqkv = (__hip_bfloat16*)(ws + 111 * MB);
    __hip_bfloat16* wprj = (__hip_bfloat16*)(ws + 122 * MB);
    __hip_bfloat16* wfc1 = (__hip_bfloat16*)(ws + 126 * MB);
    __hip_bfloat16* wfc2 = (__hip_bfloat16*)(ws + 141 * MB);
    float2* pstats = (float2*)(ws + 156 * MB);                // 12608 rows x 8 x float2
    float2* qcoef  = (float2*)(ws + 158 * MB);                // 12*1152 float2
    float2* fcoef  = (float2*)(ws + 159 * MB);                // 12*1536 float2

    k_init<<<64, 384, 0, stream>>>(si, sf, cls_tok, pos, xtA, pstats);
    k_cvtall<<<2048, 256, 0, stream>>>(patch_w, qkvw, projw, fc1w, fc2w,
                                       ln1w, ln2w,
                                       wpat, wqkv, wprj, wfc1, wfc2);
    k_lncoef<<<8064, 256, 0, stream>>>((const unsigned short*)wqkv, qkvw, ln1b,
                                       (const unsigned short*)wfc1, fc1w, ln2b,
                                       qcoef, fcoef);

    // patch embed with fused im2col (reads fp32 x directly), bf16 out (+pos), emit stats
    k_mgemm<0, 2, 0, 1><<<8 * 6 * 25, 256, 0, stream>>>(
        (const void*)x, 768, (const unsigned short*)wpat, 768,
        patch_b, xtA, kD, (const void*)pos, (const int*)nullptr,
        (const float2*)nullptr,
        196, 6, 196, (const int*)nullptr, 196,
        (const float2*)nullptr, pstats);

    unsigned short* cur = xtA; unsigned short* oth = xtB;
    for (int l = 0; l < kL; ++l) {
        const __hip_bfloat16* qw = wqkv + (size_t)l * 1152 * kD;
        const float* qb = qkvb + l * 1152;
        const __hip_bfloat16* pw = wprj + (size_t)l * kD * kD;
        const float* pb = projb + l * kD;
        const __hip_bfloat16* f1w = wfc1 + (size_t)l * 1536 * kD;
        const float* f1b = fc1b + l * 1536;
        const __hip_bfloat16* f2w = wfc2 + (size_t)l * kD * 1536;
        const float* f2b = fc2b + l * kD;

        // qkv GEMM, LN folded into weights (coef from qcoef) -> split BF16 q/k/v
        k_mgemm<0, 1, 1, 0><<<8 * 18 * 25, 256, 0, stream>>>(
            (const void*)cur, kD, (const unsigned short*)qw, kD,
            qb, (unsigned short*)qsplit, 1152, (const void*)nullptr, (const int*)nullptr,
            (const float2*)(qcoef + (size_t)l * 1152),
            197, 18, kBAND, si, 0,
            (const float2*)pstats, (float2*)nullptr);
        // decision: coalesced producers (transposed imph) + 1-block finalize
        k_decA<<<kB * kH, 256, 0, stream>>>(qsplit, imph, sabh, si);
        k_decB<<<1, 256, 0, stream>>>(si, sf, imph, sabh, keep);
        // attention on pruned tokens
        k_attn2<<<kB * kH, 256, 0, stream>>>(qsplit, obuf, si, keep);
        // proj + pruned bf16 residual (gather via keep), write other buffer, emit stats
        k_mgemm<0, 0, 0, 1><<<8 * 6 * 25, 256, 0, stream>>>(
            (const void*)obuf, kD, (const unsigned short*)pw, kD,
            pb, oth, kD, (const void*)cur, keep,
            (const float2*)nullptr,
            197, 6, kBAND, si, 0,
            (const float2*)nullptr, pstats);
        { unsigned short* tmp = cur; cur = oth; oth = tmp; }
        // fc1, LN folded into weights (coef from fcoef) -> bf16 hbuf, gelu
        k_mgemm<1, 0, 1, 0><<<8 * 24 * 25, 256, 0, stream>>>(
            (const void*)cur, kD, (const unsigned short*)f1w, kD,
            f1b, (unsigned short*)hbuf, 1536, (const void*)nullptr, (const int*)nullptr,
            (const float2*)(fcoef + (size_t)l * 1536),
            197, 24, kBAND, si, 0,
            (const float2*)pstats, (float2*)nullptr);
        // fc2 + bf16 residual (in place on cur), emit stats for next layer
        k_mgemm<0, 0, 0, 1><<<8 * 6 * 25, 256, 0, stream>>>(
            (const void*)hbuf, 1536, (const unsigned short*)f2w, 1536,
            f2b, cur, kD, (const void*)cur, (const int*)nullptr,
            (const float2*)nullptr,
            197, 6, kBAND, si, 0,
            (const float2*)nullptr, pstats);
    }

    k_head<<<kB * 4, 256, 0, stream>>>(cur, normw, normb, headw, headb, out);
}